// Round 1
// baseline (3914.569 us; speedup 1.0000x reference)
//
#include <hip/hip_runtime.h>

#define EPS 1e-5f

__device__ __forceinline__ float dot4(float4 a, float4 b) {
  return a.x * b.x + a.y * b.y + a.z * b.z + a.w * b.w;
}

// ---------------- C(MxN) = A(MxK) @ B(NxK)^T ; 64x64 tile, BK=16 ----------------
__global__ __launch_bounds__(256) void gemm_abt(const float* __restrict__ A,
                                                const float* __restrict__ B,
                                                float* __restrict__ C,
                                                int M, int N, int K) {
  __shared__ float As[16][68];
  __shared__ float Bs[16][68];
  const int t = threadIdx.x;
  const int tx = t & 15, ty = t >> 4;
  const int m0 = blockIdx.y * 64, n0 = blockIdx.x * 64;
  float acc[4][4] = {};
  for (int k0 = 0; k0 < K; k0 += 16) {
    __syncthreads();
    {
      const int r = t >> 2;
      const int kk = (t & 3) << 2;
      float4 av = *(const float4*)&A[(size_t)(m0 + r) * K + k0 + kk];
      As[kk + 0][r] = av.x; As[kk + 1][r] = av.y;
      As[kk + 2][r] = av.z; As[kk + 3][r] = av.w;
      float4 bv = *(const float4*)&B[(size_t)(n0 + r) * K + k0 + kk];
      Bs[kk + 0][r] = bv.x; Bs[kk + 1][r] = bv.y;
      Bs[kk + 2][r] = bv.z; Bs[kk + 3][r] = bv.w;
    }
    __syncthreads();
#pragma unroll
    for (int kk = 0; kk < 16; ++kk) {
      float4 a = *(const float4*)&As[kk][ty << 2];
      float4 b = *(const float4*)&Bs[kk][tx << 2];
      float av[4] = {a.x, a.y, a.z, a.w};
      float bv[4] = {b.x, b.y, b.z, b.w};
#pragma unroll
      for (int i = 0; i < 4; ++i)
#pragma unroll
        for (int j = 0; j < 4; ++j) acc[i][j] += av[i] * bv[j];
    }
  }
#pragma unroll
  for (int i = 0; i < 4; ++i) {
    float4 o = make_float4(acc[i][0], acc[i][1], acc[i][2], acc[i][3]);
    *(float4*)&C[(size_t)(m0 + (ty << 2) + i) * N + n0 + (tx << 2)] = o;
  }
}

// ---------------- per-column sum / sumsq (atomic partials) ----------------
// grid = 128 blocks, 256 threads. N in {128, 256}, M % 128 == 0.
__global__ __launch_bounds__(256) void colstats(const float* __restrict__ y,
                                                float* __restrict__ colsum,
                                                float* __restrict__ colsumsq,
                                                int M, int N) {
  const int col = threadIdx.x % N;
  const int rl = threadIdx.x / N;
  const int step = 256 / N;
  const int rpb = M / gridDim.x;
  const int r0 = blockIdx.x * rpb;
  float s = 0.f, sq = 0.f;
  for (int r = r0 + rl; r < r0 + rpb; r += step) {
    float v = y[(size_t)r * N + col];
    s += v;
    sq += v * v;
  }
  atomicAdd(&colsum[col], s);
  atomicAdd(&colsumsq[col], sq);
}

// ---------------- BN apply (+ optional relu), in place ----------------
__global__ __launch_bounds__(256) void bn_apply(float* __restrict__ y,
                                                const float* __restrict__ colsum,
                                                const float* __restrict__ colsumsq,
                                                const float* __restrict__ g,
                                                const float* __restrict__ b,
                                                int M, int N, int relu) {
  const int idx = blockIdx.x * 256 + threadIdx.x;
  const int col = idx % N;
  const float invM = 1.0f / (float)M;
  float mean = colsum[col] * invM;
  float var = colsumsq[col] * invM - mean * mean;
  float v = (y[idx] - mean) * rsqrtf(var + EPS) * g[col] + b[col];
  y[idx] = relu ? fmaxf(v, 0.f) : v;
}

// ---------------- G = x^T x for x: (M x 128). grid = 64 blocks ----------------
__global__ __launch_bounds__(256) void gram_kernel(const float* __restrict__ x,
                                                   float* __restrict__ G, int M) {
  __shared__ float xL[128 * 132];
  const int t = threadIdx.x, tx = t & 15, ty = t >> 4;
  float acc[8][8] = {};
  const int rpb = M / gridDim.x;  // 256
  for (int r0 = blockIdx.x * rpb; r0 < blockIdx.x * rpb + rpb; r0 += 128) {
    __syncthreads();
#pragma unroll
    for (int i = 0; i < 16; ++i) {
      int f4 = t + i * 256;
      int r = f4 >> 5;
      int c4 = (f4 & 31) << 2;
      *(float4*)&xL[r * 132 + c4] = *(const float4*)&x[(size_t)(r0 + r) * 128 + c4];
    }
    __syncthreads();
    for (int r = 0; r < 128; ++r) {
      float4 a0 = *(const float4*)&xL[r * 132 + ty * 8];
      float4 a1 = *(const float4*)&xL[r * 132 + ty * 8 + 4];
      float4 b0 = *(const float4*)&xL[r * 132 + tx * 8];
      float4 b1 = *(const float4*)&xL[r * 132 + tx * 8 + 4];
      float a[8] = {a0.x, a0.y, a0.z, a0.w, a1.x, a1.y, a1.z, a1.w};
      float b[8] = {b0.x, b0.y, b0.z, b0.w, b1.x, b1.y, b1.z, b1.w};
#pragma unroll
      for (int i = 0; i < 8; ++i)
#pragma unroll
        for (int j = 0; j < 8; ++j) acc[i][j] += a[i] * b[j];
    }
  }
#pragma unroll
  for (int i = 0; i < 8; ++i)
#pragma unroll
    for (int j = 0; j < 8; ++j)
      atomicAdd(&G[(ty * 8 + i) * 128 + tx * 8 + j], acc[i][j]);
}

// ---------------- finalize layer-4 BN: s,t per row; W4s = s*W4 ----------------
// one 64-lane wave per row. grid = rows/4 blocks of 256 threads.
__global__ __launch_bounds__(256) void w4_finalize(const float* __restrict__ W4,
                                                   const float* __restrict__ U,
                                                   const float* __restrict__ colsum3,
                                                   const float* __restrict__ g4,
                                                   const float* __restrict__ b4,
                                                   float* __restrict__ W4s,
                                                   float* __restrict__ t4,
                                                   int rows, float invM) {
  const int wave = (blockIdx.x * 256 + threadIdx.x) >> 6;
  const int lane = threadIdx.x & 63;
  if (wave >= rows) return;
  const float* w = W4 + (size_t)wave * 128;
  const float* u = U + (size_t)wave * 128;
  float p1 = 0.f, p2 = 0.f;
#pragma unroll
  for (int c0 = 0; c0 < 128; c0 += 64) {
    float wv = w[c0 + lane];
    p1 += u[c0 + lane] * wv;
    p2 += colsum3[c0 + lane] * wv;
  }
#pragma unroll
  for (int off = 32; off > 0; off >>= 1) {
    p1 += __shfl_down(p1, off);
    p2 += __shfl_down(p2, off);
  }
  p1 = __shfl(p1, 0);
  p2 = __shfl(p2, 0);
  float m4 = p2 * invM;          // mean of y4 column
  float q = p1 * invM;           // E[y4^2]
  float s = g4[wave] * rsqrtf(q - m4 * m4 + EPS);
  if (lane == 0) t4[wave] = b4[wave] - m4 * s;
#pragma unroll
  for (int c0 = 0; c0 < 128; c0 += 64) W4s[(size_t)wave * 128 + c0 + lane] = s * w[c0 + lane];
}

// ---------------- fused per-edge weight * message kernel ----------------
// msg[e,k] = sum_d x_i[e,d] * ( x3[e,:] . W4s[d*128+k,:] + t4[d*128+k] )
// block: 256 thr = 4 waves, 64 edges x 128 k. grid = E/64.
__global__ __launch_bounds__(256) void msg_kernel(const float* __restrict__ x3,
                                                  const float* __restrict__ node,
                                                  const int* __restrict__ eidx,
                                                  const float* __restrict__ W4s,
                                                  const float* __restrict__ t4,
                                                  float* __restrict__ msg) {
  __shared__ float x3L[64 * 132];
  __shared__ float xiL[64 * 132];
  const int t = threadIdx.x;
  const int e0 = blockIdx.x * 64;
#pragma unroll
  for (int i = 0; i < 8; ++i) {
    int f4 = t + i * 256;            // 0..2047
    int r = f4 >> 5;                 // 64 rows
    int c4 = (f4 & 31) << 2;
    *(float4*)&x3L[r * 132 + c4] = *(const float4*)&x3[(size_t)(e0 + r) * 128 + c4];
    int src = eidx[(e0 + r) * 2 + 0];
    *(float4*)&xiL[r * 132 + c4] = *(const float4*)&node[(size_t)src * 128 + c4];
  }
  __syncthreads();
  const int w = t >> 6, l = t & 63;
  const int e_loc = (w & 1) * 32 + (l >> 3) * 4;       // 4 edges per thread
  const int k_base = (w >> 1) * 64 + (l & 7) * 8;      // 8 k per thread
  float acc[4][8] = {};
  for (int d = 0; d < 128; ++d) {
    float xi[4];
#pragma unroll
    for (int i = 0; i < 4; ++i) xi[i] = xiL[(e_loc + i) * 132 + d];
    float4 tv0 = *(const float4*)&t4[d * 128 + k_base];
    float4 tv1 = *(const float4*)&t4[d * 128 + k_base + 4];
    const float* Wb = W4s + (size_t)(d * 128 + k_base) * 128;
    float y[4][8] = {};
    for (int c = 0; c < 128; c += 4) {
      float4 xv[4];
#pragma unroll
      for (int i = 0; i < 4; ++i) xv[i] = *(const float4*)&x3L[(e_loc + i) * 132 + c];
#pragma unroll
      for (int j = 0; j < 8; ++j) {
        float4 wv = *(const float4*)&Wb[j * 128 + c];
#pragma unroll
        for (int i = 0; i < 4; ++i)
          y[i][j] += xv[i].x * wv.x + xv[i].y * wv.y + xv[i].z * wv.z + xv[i].w * wv.w;
      }
    }
    float tj[8] = {tv0.x, tv0.y, tv0.z, tv0.w, tv1.x, tv1.y, tv1.z, tv1.w};
#pragma unroll
    for (int i = 0; i < 4; ++i)
#pragma unroll
      for (int j = 0; j < 8; ++j) acc[i][j] += xi[i] * (y[i][j] + tj[j]);
  }
#pragma unroll
  for (int i = 0; i < 4; ++i)
#pragma unroll
    for (int j4 = 0; j4 < 8; j4 += 4) {
      float4 o = make_float4(acc[i][j4], acc[i][j4 + 1], acc[i][j4 + 2], acc[i][j4 + 3]);
      *(float4*)&msg[(size_t)(e0 + e_loc + i) * 128 + k_base + j4] = o;
    }
}

// ---------------- segment sum (atomics) ----------------
__global__ __launch_bounds__(256) void scatter_add(const float* __restrict__ msg,
                                                   const int* __restrict__ eidx,
                                                   float* __restrict__ sums, int E) {
  int idx = blockIdx.x * 256 + threadIdx.x;
  if (idx >= E * 128) return;
  int e = idx >> 7, k = idx & 127;
  int dstn = eidx[e * 2 + 1];
  atomicAdd(&sums[(size_t)dstn * 128 + k], msg[idx]);
}

__global__ __launch_bounds__(256) void cnt_kernel(const int* __restrict__ eidx,
                                                  float* __restrict__ cnt, int E) {
  int e = blockIdx.x * 256 + threadIdx.x;
  if (e < E) atomicAdd(&cnt[eidx[e * 2 + 1]], 1.0f);
}

// ---------------- m = relu(sums/max(cnt,1) + bias) ----------------
__global__ __launch_bounds__(256) void mrelu_kernel(const float* __restrict__ sums,
                                                    const float* __restrict__ cnt,
                                                    const float* __restrict__ bias,
                                                    float* __restrict__ m) {
  int idx = blockIdx.x * 256 + threadIdx.x;
  int n = idx >> 7, k = idx & 127;
  float v = sums[idx] / fmaxf(cnt[n], 1.0f) + bias[k];
  m[idx] = fmaxf(v, 0.f);
}

// ---------------- GRU cell: 8 nodes per 128-thread block ----------------
__global__ __launch_bounds__(128) void gru_kernel(const float* __restrict__ m,
                                                  const float* __restrict__ h0,
                                                  const float* __restrict__ Wih,
                                                  const float* __restrict__ Whh,
                                                  const float* __restrict__ bih,
                                                  const float* __restrict__ bhh,
                                                  float* __restrict__ out, int Nn) {
  __shared__ float mL[8][128];
  __shared__ float hL[8][128];
  const int k = threadIdx.x;
  const int n0 = blockIdx.x * 8;
#pragma unroll
  for (int i = 0; i < 8; ++i) {
    mL[i][k] = m[(size_t)(n0 + i) * 128 + k];
    hL[i][k] = h0[(size_t)(n0 + i) * 128 + k];
  }
  __syncthreads();
  float ar[8] = {}, az[8] = {}, an[8] = {}, br[8] = {}, bz[8] = {}, bn_[8] = {};
  const float* wr = Wih + (size_t)k * 128;
  const float* wz = Wih + (size_t)(k + 128) * 128;
  const float* wn = Wih + (size_t)(k + 256) * 128;
  const float* vr = Whh + (size_t)k * 128;
  const float* vz = Whh + (size_t)(k + 128) * 128;
  const float* vn = Whh + (size_t)(k + 256) * 128;
  for (int c = 0; c < 128; c += 4) {
    float4 wr4 = *(const float4*)&wr[c];
    float4 wz4 = *(const float4*)&wz[c];
    float4 wn4 = *(const float4*)&wn[c];
    float4 vr4 = *(const float4*)&vr[c];
    float4 vz4 = *(const float4*)&vz[c];
    float4 vn4 = *(const float4*)&vn[c];
#pragma unroll
    for (int j = 0; j < 8; ++j) {
      float4 mv = *(const float4*)&mL[j][c];
      float4 hv = *(const float4*)&hL[j][c];
      ar[j] += dot4(wr4, mv);
      az[j] += dot4(wz4, mv);
      an[j] += dot4(wn4, mv);
      br[j] += dot4(vr4, hv);
      bz[j] += dot4(vz4, hv);
      bn_[j] += dot4(vn4, hv);
    }
  }
  const float bi_r = bih[k], bi_z = bih[128 + k], bi_n = bih[256 + k];
  const float bh_r = bhh[k], bh_z = bhh[128 + k], bh_n = bhh[256 + k];
#pragma unroll
  for (int j = 0; j < 8; ++j) {
    float r = 1.f / (1.f + expf(-(ar[j] + bi_r + br[j] + bh_r)));
    float z = 1.f / (1.f + expf(-(az[j] + bi_z + bz[j] + bh_z)));
    float nn = tanhf(an[j] + bi_n + r * (bn_[j] + bh_n));
    float h = hL[j][k];
    float hn = (1.f - z) * nn + z * h;
    size_t o = (size_t)(n0 + j) * 128 + k;
    out[o] = hn;
    out[o + (size_t)Nn * 128] = hn;
  }
}

extern "C" void kernel_launch(void* const* d_in, const int* in_sizes, int n_in,
                              void* d_out, int out_size, void* d_ws, size_t ws_size,
                              hipStream_t stream) {
  const float* node = (const float*)d_in[0];
  const int* eidx = (const int*)d_in[1];
  const float* edge = (const float*)d_in[2];
  const float* hidden = (const float*)d_in[3];
  const float* W1 = (const float*)d_in[4];
  const float* g1 = (const float*)d_in[5];
  const float* b1 = (const float*)d_in[6];
  const float* W2 = (const float*)d_in[7];
  const float* g2 = (const float*)d_in[8];
  const float* b2 = (const float*)d_in[9];
  const float* W3 = (const float*)d_in[10];
  const float* g3 = (const float*)d_in[11];
  const float* b3 = (const float*)d_in[12];
  const float* W4 = (const float*)d_in[13];
  const float* g4 = (const float*)d_in[14];
  const float* b4 = (const float*)d_in[15];
  const float* bias = (const float*)d_in[16];
  const float* Wih = (const float*)d_in[17];
  const float* Whh = (const float*)d_in[18];
  const float* bih = (const float*)d_in[19];
  const float* bhh = (const float*)d_in[20];
  float* out = (float*)d_out;

  const int Nn = in_sizes[0] / 128;   // 4096
  const int E = in_sizes[2] / 16;     // 16384

  float* ws = (float*)d_ws;
  float* ybuf1 = ws + 0;                       // E x 256   (y1/x1; later msg)
  float* ybuf2 = ws + 4194304;                 // E x 256   (y2/x2; later U)
  float* x3 = ws + 8388608;                    // E x 128
  float* W4s = ws + 10485760;                  // 16384 x 128
  float* t4 = ws + 12582912;                   // 16384
  float* stat = ws + 12599296;                 // 512 (colsum, colsumsq)
  float* G3 = ws + 12599808;                   // 128 x 128
  float* sums = ws + 12616192;                 // Nn x 128
  float* cnt = ws + 13140480;                  // Nn
  float* mrow = ws + 13144576;                 // Nn x 128

  // ---- layer 1: y1 = edge @ W1^T ; BN+relu ----
  gemm_abt<<<dim3(256 / 64, E / 64), 256, 0, stream>>>(edge, W1, ybuf1, E, 256, 16);
  hipMemsetAsync(stat, 0, 512 * sizeof(float), stream);
  colstats<<<128, 256, 0, stream>>>(ybuf1, stat, stat + 256, E, 256);
  bn_apply<<<E * 256 / 256, 256, 0, stream>>>(ybuf1, stat, stat + 256, g1, b1, E, 256, 1);

  // ---- layer 2 ----
  gemm_abt<<<dim3(256 / 64, E / 64), 256, 0, stream>>>(ybuf1, W2, ybuf2, E, 256, 256);
  hipMemsetAsync(stat, 0, 512 * sizeof(float), stream);
  colstats<<<128, 256, 0, stream>>>(ybuf2, stat, stat + 256, E, 256);
  bn_apply<<<E * 256 / 256, 256, 0, stream>>>(ybuf2, stat, stat + 256, g2, b2, E, 256, 1);

  // ---- layer 3 ----
  gemm_abt<<<dim3(128 / 64, E / 64), 256, 0, stream>>>(ybuf2, W3, x3, E, 128, 256);
  hipMemsetAsync(stat, 0, 512 * sizeof(float), stream);
  colstats<<<128, 256, 0, stream>>>(x3, stat, stat + 256, E, 128);
  bn_apply<<<E * 128 / 256, 256, 0, stream>>>(x3, stat, stat + 256, g3, b3, E, 128, 1);

  // ---- layer-4 BN stats via Gram trick ----
  hipMemsetAsync(stat, 0, 512 * sizeof(float), stream);
  colstats<<<128, 256, 0, stream>>>(x3, stat, stat + 256, E, 128);       // colsum3
  hipMemsetAsync(G3, 0, 16384 * sizeof(float), stream);
  gram_kernel<<<64, 256, 0, stream>>>(x3, G3, E);
  gemm_abt<<<dim3(128 / 64, 16384 / 64), 256, 0, stream>>>(W4, G3, ybuf2, 16384, 128, 128);  // U
  w4_finalize<<<16384 / 4, 256, 0, stream>>>(W4, ybuf2, stat, g4, b4, W4s, t4, 16384,
                                             1.0f / (float)E);

  // ---- fused per-edge message ----
  msg_kernel<<<E / 64, 256, 0, stream>>>(x3, node, eidx, W4s, t4, ybuf1);

  // ---- segment mean ----
  hipMemsetAsync(sums, 0, (size_t)Nn * 128 * sizeof(float), stream);
  hipMemsetAsync(cnt, 0, (size_t)Nn * sizeof(float), stream);
  scatter_add<<<E * 128 / 256, 256, 0, stream>>>(ybuf1, eidx, sums, E);
  cnt_kernel<<<(E + 255) / 256, 256, 0, stream>>>(eidx, cnt, E);
  mrelu_kernel<<<Nn * 128 / 256, 256, 0, stream>>>(sums, cnt, bias, mrow);

  // ---- GRU ----
  gru_kernel<<<Nn / 8, 128, 0, stream>>>(mrow, hidden, Wih, Whh, bih, bhh, out, Nn);
}

// Round 2
// 582.368 us; speedup vs baseline: 6.7218x; 6.7218x over previous
//
#include <hip/hip_runtime.h>

#define EPS 1e-5f

typedef _Float16 half8 __attribute__((ext_vector_type(8)));
typedef float f32x4 __attribute__((ext_vector_type(4)));

__device__ __forceinline__ float dot4(float4 a, float4 b) {
  return a.x * b.x + a.y * b.y + a.z * b.z + a.w * b.w;
}

// ---------------- C(MxN) = A(MxK) @ B(NxK)^T ; 64x64 tile, BK=16 ----------------
__global__ __launch_bounds__(256) void gemm_abt(const float* __restrict__ A,
                                                const float* __restrict__ B,
                                                float* __restrict__ C,
                                                int M, int N, int K) {
  __shared__ float As[16][68];
  __shared__ float Bs[16][68];
  const int t = threadIdx.x;
  const int tx = t & 15, ty = t >> 4;
  const int m0 = blockIdx.y * 64, n0 = blockIdx.x * 64;
  float acc[4][4] = {};
  for (int k0 = 0; k0 < K; k0 += 16) {
    __syncthreads();
    {
      const int r = t >> 2;
      const int kk = (t & 3) << 2;
      float4 av = *(const float4*)&A[(size_t)(m0 + r) * K + k0 + kk];
      As[kk + 0][r] = av.x; As[kk + 1][r] = av.y;
      As[kk + 2][r] = av.z; As[kk + 3][r] = av.w;
      float4 bv = *(const float4*)&B[(size_t)(n0 + r) * K + k0 + kk];
      Bs[kk + 0][r] = bv.x; Bs[kk + 1][r] = bv.y;
      Bs[kk + 2][r] = bv.z; Bs[kk + 3][r] = bv.w;
    }
    __syncthreads();
#pragma unroll
    for (int kk = 0; kk < 16; ++kk) {
      float4 a = *(const float4*)&As[kk][ty << 2];
      float4 b = *(const float4*)&Bs[kk][tx << 2];
      float av[4] = {a.x, a.y, a.z, a.w};
      float bv[4] = {b.x, b.y, b.z, b.w};
#pragma unroll
      for (int i = 0; i < 4; ++i)
#pragma unroll
        for (int j = 0; j < 4; ++j) acc[i][j] += av[i] * bv[j];
    }
  }
#pragma unroll
  for (int i = 0; i < 4; ++i) {
    float4 o = make_float4(acc[i][0], acc[i][1], acc[i][2], acc[i][3]);
    *(float4*)&C[(size_t)(m0 + (ty << 2) + i) * N + n0 + (tx << 2)] = o;
  }
}

// ---------------- per-column sum / sumsq (atomic partials) ----------------
__global__ __launch_bounds__(256) void colstats(const float* __restrict__ y,
                                                float* __restrict__ colsum,
                                                float* __restrict__ colsumsq,
                                                int M, int N) {
  const int col = threadIdx.x % N;
  const int rl = threadIdx.x / N;
  const int step = 256 / N;
  const int rpb = M / gridDim.x;
  const int r0 = blockIdx.x * rpb;
  float s = 0.f, sq = 0.f;
  for (int r = r0 + rl; r < r0 + rpb; r += step) {
    float v = y[(size_t)r * N + col];
    s += v;
    sq += v * v;
  }
  atomicAdd(&colsum[col], s);
  atomicAdd(&colsumsq[col], sq);
}

// ---------------- BN apply (+ optional relu), in place ----------------
__global__ __launch_bounds__(256) void bn_apply(float* __restrict__ y,
                                                const float* __restrict__ colsum,
                                                const float* __restrict__ colsumsq,
                                                const float* __restrict__ g,
                                                const float* __restrict__ b,
                                                int M, int N, int relu) {
  const int idx = blockIdx.x * 256 + threadIdx.x;
  const int col = idx % N;
  const float invM = 1.0f / (float)M;
  float mean = colsum[col] * invM;
  float var = colsumsq[col] * invM - mean * mean;
  float v = (y[idx] - mean) * rsqrtf(var + EPS) * g[col] + b[col];
  y[idx] = relu ? fmaxf(v, 0.f) : v;
}

// ---------------- G = x^T x for x: (M x 128). grid = 64 blocks ----------------
__global__ __launch_bounds__(256) void gram_kernel(const float* __restrict__ x,
                                                   float* __restrict__ G, int M) {
  __shared__ float xL[128 * 132];
  const int t = threadIdx.x, tx = t & 15, ty = t >> 4;
  float acc[8][8] = {};
  const int rpb = M / gridDim.x;  // 256
  for (int r0 = blockIdx.x * rpb; r0 < blockIdx.x * rpb + rpb; r0 += 128) {
    __syncthreads();
#pragma unroll
    for (int i = 0; i < 16; ++i) {
      int f4 = t + i * 256;
      int r = f4 >> 5;
      int c4 = (f4 & 31) << 2;
      *(float4*)&xL[r * 132 + c4] = *(const float4*)&x[(size_t)(r0 + r) * 128 + c4];
    }
    __syncthreads();
    for (int r = 0; r < 128; ++r) {
      float4 a0 = *(const float4*)&xL[r * 132 + ty * 8];
      float4 a1 = *(const float4*)&xL[r * 132 + ty * 8 + 4];
      float4 b0 = *(const float4*)&xL[r * 132 + tx * 8];
      float4 b1 = *(const float4*)&xL[r * 132 + tx * 8 + 4];
      float a[8] = {a0.x, a0.y, a0.z, a0.w, a1.x, a1.y, a1.z, a1.w};
      float b[8] = {b0.x, b0.y, b0.z, b0.w, b1.x, b1.y, b1.z, b1.w};
#pragma unroll
      for (int i = 0; i < 8; ++i)
#pragma unroll
        for (int j = 0; j < 8; ++j) acc[i][j] += a[i] * b[j];
    }
  }
#pragma unroll
  for (int i = 0; i < 8; ++i)
#pragma unroll
    for (int j = 0; j < 8; ++j)
      atomicAdd(&G[(ty * 8 + i) * 128 + tx * 8 + j], acc[i][j]);
}

// ---------------- finalize layer-4 BN; emit BT (fp16, [kout][16384]) + t4 ----------------
// BT[kout][d*128+c] = s(d*128+kout) * W4[d*128+kout][c];  t4[r] = b4 - m4*s
__global__ __launch_bounds__(256) void w4_finalize(const float* __restrict__ W4,
                                                   const float* __restrict__ U,
                                                   const float* __restrict__ colsum3,
                                                   const float* __restrict__ g4,
                                                   const float* __restrict__ b4,
                                                   _Float16* __restrict__ BT,
                                                   float* __restrict__ t4,
                                                   float invM) {
  const int r = (blockIdx.x * 256 + threadIdx.x) >> 6;   // 0..16383
  const int lane = threadIdx.x & 63;
  const float* w = W4 + (size_t)r * 128;
  const float* u = U + (size_t)r * 128;
  float p1 = 0.f, p2 = 0.f;
#pragma unroll
  for (int c0 = 0; c0 < 128; c0 += 64) {
    float wv = w[c0 + lane];
    p1 += u[c0 + lane] * wv;
    p2 += colsum3[c0 + lane] * wv;
  }
#pragma unroll
  for (int off = 32; off > 0; off >>= 1) {
    p1 += __shfl_down(p1, off);
    p2 += __shfl_down(p2, off);
  }
  p1 = __shfl(p1, 0);
  p2 = __shfl(p2, 0);
  float m4 = p2 * invM;
  float q = p1 * invM;
  float s = g4[r] * rsqrtf(q - m4 * m4 + EPS);
  if (lane == 0) t4[r] = b4[r] - m4 * s;
  const int kout = r & 127, d = r >> 7;
  _Float16* bp = BT + (size_t)kout * 16384 + d * 128;
#pragma unroll
  for (int c0 = 0; c0 < 128; c0 += 64) bp[c0 + lane] = (_Float16)(s * w[c0 + lane]);
}

// ---------------- msg = Z @ B via MFMA; Z[e, d*128+c] = xi[e,d]*x3[e,c] on the fly ----
// grid = (KSPLIT=4, E/128); block 256 = 4 waves (2x2 of 64x64). BK=128 (one d per tile).
__global__ __launch_bounds__(256) void zgemm(const float* __restrict__ x3,
                                             const float* __restrict__ node,
                                             const int* __restrict__ eidx,
                                             const _Float16* __restrict__ BT,
                                             float* __restrict__ msg) {
  __shared__ _Float16 As[128 * 128];
  __shared__ _Float16 Bs[128 * 128];
  __shared__ _Float16 xiL[128 * 34];
  const int t = threadIdx.x;
  const int e0 = blockIdx.y * 128;
  const int kc0 = blockIdx.x * 4096;
  const int d0 = kc0 >> 7;  // 32 d-values per chunk
  // preload xi[e][d0..d0+31] as fp16
  {
    const int e = t >> 1, dl0 = (t & 1) * 16;
    const int src = eidx[(e0 + e) * 2];
    const float* np = node + (size_t)src * 128 + d0 + dl0;
#pragma unroll
    for (int j = 0; j < 16; j += 4) {
      float4 v = *(const float4*)(np + j);
      xiL[e * 34 + dl0 + j + 0] = (_Float16)v.x;
      xiL[e * 34 + dl0 + j + 1] = (_Float16)v.y;
      xiL[e * 34 + dl0 + j + 2] = (_Float16)v.z;
      xiL[e * 34 + dl0 + j + 3] = (_Float16)v.w;
    }
  }
  f32x4 acc[4][4];
#pragma unroll
  for (int i = 0; i < 4; ++i)
#pragma unroll
    for (int j = 0; j < 4; ++j) acc[i][j] = (f32x4){0.f, 0.f, 0.f, 0.f};
  const int w = t >> 6, l = t & 63;
  const int m0w = (w & 1) * 64, n0w = (w >> 1) * 64;
  const int lr = l & 15, lg = l >> 4;

  for (int kt = 0; kt < 4096; kt += 128) {
    const int dl = kt >> 7;
    const int k0 = kc0 + kt;
    __syncthreads();
    // stage A: As[row e][kk=c] = xi[e][dl] * x3[e0+e][kk], fp16, XOR-swizzled
#pragma unroll
    for (int i = 0; i < 8; ++i) {
      int q = i * 256 + t;           // 2048 chunks of 8 halves
      int row = q >> 4;
      int cq = q & 15;
      float xiv = (float)xiL[row * 34 + dl];
      const float* xp = x3 + (size_t)(e0 + row) * 128 + cq * 8;
      float4 a = *(const float4*)xp;
      float4 b = *(const float4*)(xp + 4);
      half8 h;
      h[0] = (_Float16)(xiv * a.x); h[1] = (_Float16)(xiv * a.y);
      h[2] = (_Float16)(xiv * a.z); h[3] = (_Float16)(xiv * a.w);
      h[4] = (_Float16)(xiv * b.x); h[5] = (_Float16)(xiv * b.y);
      h[6] = (_Float16)(xiv * b.z); h[7] = (_Float16)(xiv * b.w);
      int byte = ((row << 8) + (cq << 4)) ^ ((row & 7) << 4);
      *(half8*)((char*)As + byte) = h;
      // stage B: Bs[row n][kk] = BT[n][k0+kk]
      half8 bv = *(const half8*)(BT + (size_t)row * 16384 + k0 + cq * 8);
      *(half8*)((char*)Bs + byte) = bv;
    }
    __syncthreads();
#pragma unroll
    for (int ks = 0; ks < 4; ++ks) {
      half8 af[4], bf[4];
#pragma unroll
      for (int i = 0; i < 4; ++i) {
        int rowA = m0w + i * 16 + lr;
        int byteA = (rowA * 256 + ks * 64 + lg * 16) ^ ((rowA & 7) << 4);
        af[i] = *(half8*)((char*)As + byteA);
        int rowB = n0w + i * 16 + lr;
        int byteB = (rowB * 256 + ks * 64 + lg * 16) ^ ((rowB & 7) << 4);
        bf[i] = *(half8*)((char*)Bs + byteB);
      }
#pragma unroll
      for (int i = 0; i < 4; ++i)
#pragma unroll
        for (int j = 0; j < 4; ++j)
          acc[i][j] = __builtin_amdgcn_mfma_f32_16x16x32_f16(af[i], bf[j], acc[i][j], 0, 0, 0);
    }
  }
  // epilogue: D layout col = lane&15, row = (lane>>4)*4 + reg  (split-K -> atomic)
#pragma unroll
  for (int i = 0; i < 4; ++i)
#pragma unroll
    for (int j = 0; j < 4; ++j)
#pragma unroll
      for (int r = 0; r < 4; ++r) {
        int erow = m0w + i * 16 + lg * 4 + r;
        int kcol = n0w + j * 16 + lr;
        atomicAdd(&msg[(size_t)(e0 + erow) * 128 + kcol], acc[i][j][r]);
      }
}

// ---------------- Tn = node @ t4mat  (t4mat[d][k] = t4[d*128+k]) ----------------
__global__ __launch_bounds__(128) void t4n_kernel(const float* __restrict__ node,
                                                  const float* __restrict__ t4,
                                                  float* __restrict__ Tn) {
  __shared__ float nodeL[8][128];
  const int k = threadIdx.x;
  const int n0 = blockIdx.x * 8;
#pragma unroll
  for (int j = 0; j < 8; ++j) nodeL[j][k] = node[(size_t)(n0 + j) * 128 + k];
  __syncthreads();
  float acc[8] = {};
  for (int d = 0; d < 128; ++d) {
    float wv = t4[d * 128 + k];
#pragma unroll
    for (int j = 0; j < 8; ++j) acc[j] += nodeL[j][d] * wv;
  }
#pragma unroll
  for (int j = 0; j < 8; ++j) Tn[(size_t)(n0 + j) * 128 + k] = acc[j];
}

// ---------------- segment sum (atomics), msg + Tn[src] gathered ----------------
__global__ __launch_bounds__(256) void scatter_add(const float* __restrict__ msg,
                                                   const float* __restrict__ Tn,
                                                   const int* __restrict__ eidx,
                                                   float* __restrict__ sums, int E) {
  int idx = blockIdx.x * 256 + threadIdx.x;
  if (idx >= E * 128) return;
  int e = idx >> 7, k = idx & 127;
  int src = eidx[e * 2 + 0];
  int dstn = eidx[e * 2 + 1];
  atomicAdd(&sums[(size_t)dstn * 128 + k], msg[idx] + Tn[(size_t)src * 128 + k]);
}

__global__ __launch_bounds__(256) void cnt_kernel(const int* __restrict__ eidx,
                                                  float* __restrict__ cnt, int E) {
  int e = blockIdx.x * 256 + threadIdx.x;
  if (e < E) atomicAdd(&cnt[eidx[e * 2 + 1]], 1.0f);
}

// ---------------- m = relu(sums/max(cnt,1) + bias) ----------------
__global__ __launch_bounds__(256) void mrelu_kernel(const float* __restrict__ sums,
                                                    const float* __restrict__ cnt,
                                                    const float* __restrict__ bias,
                                                    float* __restrict__ m) {
  int idx = blockIdx.x * 256 + threadIdx.x;
  int n = idx >> 7, k = idx & 127;
  float v = sums[idx] / fmaxf(cnt[n], 1.0f) + bias[k];
  m[idx] = fmaxf(v, 0.f);
}

// ---------------- GRU cell: 8 nodes per 128-thread block ----------------
__global__ __launch_bounds__(128) void gru_kernel(const float* __restrict__ m,
                                                  const float* __restrict__ h0,
                                                  const float* __restrict__ Wih,
                                                  const float* __restrict__ Whh,
                                                  const float* __restrict__ bih,
                                                  const float* __restrict__ bhh,
                                                  float* __restrict__ out, int Nn) {
  __shared__ float mL[8][128];
  __shared__ float hL[8][128];
  const int k = threadIdx.x;
  const int n0 = blockIdx.x * 8;
#pragma unroll
  for (int i = 0; i < 8; ++i) {
    mL[i][k] = m[(size_t)(n0 + i) * 128 + k];
    hL[i][k] = h0[(size_t)(n0 + i) * 128 + k];
  }
  __syncthreads();
  float ar[8] = {}, az[8] = {}, an[8] = {}, br[8] = {}, bz[8] = {}, bn_[8] = {};
  const float* wr = Wih + (size_t)k * 128;
  const float* wz = Wih + (size_t)(k + 128) * 128;
  const float* wn = Wih + (size_t)(k + 256) * 128;
  const float* vr = Whh + (size_t)k * 128;
  const float* vz = Whh + (size_t)(k + 128) * 128;
  const float* vn = Whh + (size_t)(k + 256) * 128;
  for (int c = 0; c < 128; c += 4) {
    float4 wr4 = *(const float4*)&wr[c];
    float4 wz4 = *(const float4*)&wz[c];
    float4 wn4 = *(const float4*)&wn[c];
    float4 vr4 = *(const float4*)&vr[c];
    float4 vz4 = *(const float4*)&vz[c];
    float4 vn4 = *(const float4*)&vn[c];
#pragma unroll
    for (int j = 0; j < 8; ++j) {
      float4 mv = *(const float4*)&mL[j][c];
      float4 hv = *(const float4*)&hL[j][c];
      ar[j] += dot4(wr4, mv);
      az[j] += dot4(wz4, mv);
      an[j] += dot4(wn4, mv);
      br[j] += dot4(vr4, hv);
      bz[j] += dot4(vz4, hv);
      bn_[j] += dot4(vn4, hv);
    }
  }
  const float bi_r = bih[k], bi_z = bih[128 + k], bi_n = bih[256 + k];
  const float bh_r = bhh[k], bh_z = bhh[128 + k], bh_n = bhh[256 + k];
#pragma unroll
  for (int j = 0; j < 8; ++j) {
    float r = 1.f / (1.f + expf(-(ar[j] + bi_r + br[j] + bh_r)));
    float z = 1.f / (1.f + expf(-(az[j] + bi_z + bz[j] + bh_z)));
    float nn = tanhf(an[j] + bi_n + r * (bn_[j] + bh_n));
    float h = hL[j][k];
    float hn = (1.f - z) * nn + z * h;
    size_t o = (size_t)(n0 + j) * 128 + k;
    out[o] = hn;
    out[o + (size_t)Nn * 128] = hn;
  }
}

extern "C" void kernel_launch(void* const* d_in, const int* in_sizes, int n_in,
                              void* d_out, int out_size, void* d_ws, size_t ws_size,
                              hipStream_t stream) {
  const float* node = (const float*)d_in[0];
  const int* eidx = (const int*)d_in[1];
  const float* edge = (const float*)d_in[2];
  const float* hidden = (const float*)d_in[3];
  const float* W1 = (const float*)d_in[4];
  const float* g1 = (const float*)d_in[5];
  const float* b1 = (const float*)d_in[6];
  const float* W2 = (const float*)d_in[7];
  const float* g2 = (const float*)d_in[8];
  const float* b2 = (const float*)d_in[9];
  const float* W3 = (const float*)d_in[10];
  const float* g3 = (const float*)d_in[11];
  const float* b3 = (const float*)d_in[12];
  const float* W4 = (const float*)d_in[13];
  const float* g4 = (const float*)d_in[14];
  const float* b4 = (const float*)d_in[15];
  const float* bias = (const float*)d_in[16];
  const float* Wih = (const float*)d_in[17];
  const float* Whh = (const float*)d_in[18];
  const float* bih = (const float*)d_in[19];
  const float* bhh = (const float*)d_in[20];
  float* out = (float*)d_out;

  const int Nn = in_sizes[0] / 128;   // 4096
  const int E = in_sizes[2] / 16;     // 16384

  float* ws = (float*)d_ws;
  float* ybuf1 = ws + 0;                       // E x 256 (y1/x1; later msg Ex128)
  float* ybuf2 = ws + 4194304;                 // E x 256 (y2/x2; later U)
  float* x3 = ws + 8388608;                    // E x 128
  _Float16* BT16 = (_Float16*)(ws + 10485760); // 128 x 16384 fp16 (1,048,576 floats)
  float* t4 = ws + 11534336;                   // 16384
  float* stat = ws + 11550720;                 // 512
  float* G3 = ws + 11551232;                   // 128 x 128
  float* sums = ws + 11567616;                 // Nn x 128
  float* cnt = ws + 12091904;                  // Nn
  float* mrow = ws + 12096000;                 // Nn x 128
  float* Tn = ws + 12620288;                   // Nn x 128

  // ---- layer 1: y1 = edge @ W1^T ; BN+relu ----
  gemm_abt<<<dim3(256 / 64, E / 64), 256, 0, stream>>>(edge, W1, ybuf1, E, 256, 16);
  hipMemsetAsync(stat, 0, 512 * sizeof(float), stream);
  colstats<<<128, 256, 0, stream>>>(ybuf1, stat, stat + 256, E, 256);
  bn_apply<<<E * 256 / 256, 256, 0, stream>>>(ybuf1, stat, stat + 256, g1, b1, E, 256, 1);

  // ---- layer 2 ----
  gemm_abt<<<dim3(256 / 64, E / 64), 256, 0, stream>>>(ybuf1, W2, ybuf2, E, 256, 256);
  hipMemsetAsync(stat, 0, 512 * sizeof(float), stream);
  colstats<<<128, 256, 0, stream>>>(ybuf2, stat, stat + 256, E, 256);
  bn_apply<<<E * 256 / 256, 256, 0, stream>>>(ybuf2, stat, stat + 256, g2, b2, E, 256, 1);

  // ---- layer 3 ----
  gemm_abt<<<dim3(128 / 64, E / 64), 256, 0, stream>>>(ybuf2, W3, x3, E, 128, 256);
  hipMemsetAsync(stat, 0, 512 * sizeof(float), stream);
  colstats<<<128, 256, 0, stream>>>(x3, stat, stat + 256, E, 128);
  bn_apply<<<E * 128 / 256, 256, 0, stream>>>(x3, stat, stat + 256, g3, b3, E, 128, 1);

  // ---- layer-4 BN stats via Gram trick; emit BT fp16 + t4 ----
  hipMemsetAsync(stat, 0, 512 * sizeof(float), stream);
  colstats<<<128, 256, 0, stream>>>(x3, stat, stat + 256, E, 128);       // colsum3
  hipMemsetAsync(G3, 0, 16384 * sizeof(float), stream);
  gram_kernel<<<64, 256, 0, stream>>>(x3, G3, E);
  gemm_abt<<<dim3(128 / 64, 16384 / 64), 256, 0, stream>>>(W4, G3, ybuf2, 16384, 128, 128);
  w4_finalize<<<16384 / 4, 256, 0, stream>>>(W4, ybuf2, stat, g4, b4, BT16, t4,
                                             1.0f / (float)E);

  // ---- fused message GEMM (split-K=4, atomic f32) ----
  hipMemsetAsync(ybuf1, 0, (size_t)E * 128 * sizeof(float), stream);
  zgemm<<<dim3(4, E / 128), 256, 0, stream>>>(x3, node, eidx, BT16, ybuf1);
  t4n_kernel<<<Nn / 8, 128, 0, stream>>>(node, t4, Tn);

  // ---- segment mean ----
  hipMemsetAsync(sums, 0, (size_t)Nn * 128 * sizeof(float), stream);
  hipMemsetAsync(cnt, 0, (size_t)Nn * sizeof(float), stream);
  scatter_add<<<E * 128 / 256, 256, 0, stream>>>(ybuf1, Tn, eidx, sums, E);
  cnt_kernel<<<(E + 255) / 256, 256, 0, stream>>>(eidx, cnt, E);
  mrelu_kernel<<<Nn * 128 / 256, 256, 0, stream>>>(sums, cnt, bias, mrow);

  // ---- GRU ----
  gru_kernel<<<Nn / 8, 128, 0, stream>>>(mrow, hidden, Wih, Whh, bih, bhh, out, Nn);
}

// Round 3
// 401.232 us; speedup vs baseline: 9.7564x; 1.4515x over previous
//
#include <hip/hip_runtime.h>

#define EPS 1e-5f

typedef _Float16 half8 __attribute__((ext_vector_type(8)));
typedef float f32x16 __attribute__((ext_vector_type(16)));

// ---------------- C(MxN) = A(MxK) @ B(NxK)^T ; 64x64 tile, BK=16, f32 (L1 only) ----------------
__global__ __launch_bounds__(256) void gemm_abt(const float* __restrict__ A,
                                                const float* __restrict__ B,
                                                float* __restrict__ C,
                                                int M, int N, int K) {
  __shared__ float As[16][68];
  __shared__ float Bs[16][68];
  const int t = threadIdx.x;
  const int tx = t & 15, ty = t >> 4;
  const int m0 = blockIdx.y * 64, n0 = blockIdx.x * 64;
  float acc[4][4] = {};
  for (int k0 = 0; k0 < K; k0 += 16) {
    __syncthreads();
    {
      const int r = t >> 2;
      const int kk = (t & 3) << 2;
      float4 av = *(const float4*)&A[(size_t)(m0 + r) * K + k0 + kk];
      As[kk + 0][r] = av.x; As[kk + 1][r] = av.y;
      As[kk + 2][r] = av.z; As[kk + 3][r] = av.w;
      float4 bv = *(const float4*)&B[(size_t)(n0 + r) * K + k0 + kk];
      Bs[kk + 0][r] = bv.x; Bs[kk + 1][r] = bv.y;
      Bs[kk + 2][r] = bv.z; Bs[kk + 3][r] = bv.w;
    }
    __syncthreads();
#pragma unroll
    for (int kk = 0; kk < 16; ++kk) {
      float4 a = *(const float4*)&As[kk][ty << 2];
      float4 b = *(const float4*)&Bs[kk][tx << 2];
      float av[4] = {a.x, a.y, a.z, a.w};
      float bv[4] = {b.x, b.y, b.z, b.w};
#pragma unroll
      for (int i = 0; i < 4; ++i)
#pragma unroll
        for (int j = 0; j < 4; ++j) acc[i][j] += av[i] * bv[j];
    }
  }
#pragma unroll
  for (int i = 0; i < 4; ++i) {
    float4 o = make_float4(acc[i][0], acc[i][1], acc[i][2], acc[i][3]);
    *(float4*)&C[(size_t)(m0 + (ty << 2) + i) * N + n0 + (tx << 2)] = o;
  }
}

// ---------------- MFMA fp16 GEMM: C(f32) = A(f32,MxK) @ B(f32,NxK)^T ----------------
// tile 128x128, BK=64, 4 waves (2x2 of 64x64), fragment-major LDS (conflict-free).
__global__ __launch_bounds__(256) void gemm16(const float* __restrict__ A,
                                              const float* __restrict__ B,
                                              float* __restrict__ C,
                                              int lda, int ldb, int ldc, int K) {
  __shared__ _Float16 As[128 * 64];
  __shared__ _Float16 Bs[128 * 64];
  const int t = threadIdx.x;
  const int m0 = blockIdx.y * 128, n0 = blockIdx.x * 128;
  const int w = t >> 6, l = t & 63;
  const int wm = w >> 1, wn = w & 1;
  const int lr = l & 31, lg = l >> 5;
  f32x16 acc[2][2];
#pragma unroll
  for (int i = 0; i < 2; ++i)
#pragma unroll
    for (int j = 0; j < 2; ++j) acc[i][j] = (f32x16){0.f};
  for (int k0 = 0; k0 < K; k0 += 64) {
    __syncthreads();
#pragma unroll
    for (int i = 0; i < 4; ++i) {
      const int g = i * 256 + t;
      const int f = g >> 6, lp = g & 63;
      const int row = (f >> 2) * 32 + (lp & 31);
      const int c = (f & 3) * 16 + (lp >> 5) * 8;
      const float* ap = A + (size_t)(m0 + row) * lda + k0 + c;
      float4 a = *(const float4*)ap, b = *(const float4*)(ap + 4);
      half8 h;
      h[0] = (_Float16)a.x; h[1] = (_Float16)a.y; h[2] = (_Float16)a.z; h[3] = (_Float16)a.w;
      h[4] = (_Float16)b.x; h[5] = (_Float16)b.y; h[6] = (_Float16)b.z; h[7] = (_Float16)b.w;
      *(half8*)(As + (size_t)g * 8) = h;
      const float* bp = B + (size_t)(n0 + row) * ldb + k0 + c;
      float4 e = *(const float4*)bp, f4 = *(const float4*)(bp + 4);
      half8 hb;
      hb[0] = (_Float16)e.x; hb[1] = (_Float16)e.y; hb[2] = (_Float16)e.z; hb[3] = (_Float16)e.w;
      hb[4] = (_Float16)f4.x; hb[5] = (_Float16)f4.y; hb[6] = (_Float16)f4.z; hb[7] = (_Float16)f4.w;
      *(half8*)(Bs + (size_t)g * 8) = hb;
    }
    __syncthreads();
#pragma unroll
    for (int ks = 0; ks < 4; ++ks) {
      half8 af[2], bf[2];
#pragma unroll
      for (int mb = 0; mb < 2; ++mb) {
        const int fa = ((wm * 2 + mb) * 4 + ks);
        af[mb] = *(const half8*)(As + (size_t)(fa * 64 + l) * 8);
        const int fb = ((wn * 2 + mb) * 4 + ks);
        bf[mb] = *(const half8*)(Bs + (size_t)(fb * 64 + l) * 8);
      }
#pragma unroll
      for (int mb = 0; mb < 2; ++mb)
#pragma unroll
        for (int nb = 0; nb < 2; ++nb)
          acc[mb][nb] = __builtin_amdgcn_mfma_f32_32x32x16_f16(af[mb], bf[nb], acc[mb][nb], 0, 0, 0);
    }
  }
#pragma unroll
  for (int mb = 0; mb < 2; ++mb)
#pragma unroll
    for (int nb = 0; nb < 2; ++nb)
#pragma unroll
      for (int r = 0; r < 16; ++r) {
        const int row = m0 + wm * 64 + mb * 32 + (r & 3) + 8 * (r >> 2) + 4 * lg;
        const int col = n0 + wn * 64 + nb * 32 + lr;
        C[(size_t)row * ldc + col] = acc[mb][nb][r];
      }
}

// ---------------- per-column sum / sumsq (atomic partials) ----------------
__global__ __launch_bounds__(256) void colstats(const float* __restrict__ y,
                                                float* __restrict__ colsum,
                                                float* __restrict__ colsumsq,
                                                int M, int N) {
  const int col = threadIdx.x % N;
  const int rl = threadIdx.x / N;
  const int step = 256 / N;
  const int rpb = M / gridDim.x;
  const int r0 = blockIdx.x * rpb;
  float s = 0.f, sq = 0.f;
  for (int r = r0 + rl; r < r0 + rpb; r += step) {
    float v = y[(size_t)r * N + col];
    s += v;
    sq += v * v;
  }
  atomicAdd(&colsum[col], s);
  atomicAdd(&colsumsq[col], sq);
}

// ---------------- BN apply (+ optional relu), in place ----------------
__global__ __launch_bounds__(256) void bn_apply(float* __restrict__ y,
                                                const float* __restrict__ colsum,
                                                const float* __restrict__ colsumsq,
                                                const float* __restrict__ g,
                                                const float* __restrict__ b,
                                                int M, int N, int relu) {
  const int idx = blockIdx.x * 256 + threadIdx.x;
  const int col = idx % N;
  const float invM = 1.0f / (float)M;
  float mean = colsum[col] * invM;
  float var = colsumsq[col] * invM - mean * mean;
  float v = (y[idx] - mean) * rsqrtf(var + EPS) * g[col] + b[col];
  y[idx] = relu ? fmaxf(v, 0.f) : v;
}

// ---------------- G = x^T x for x: (M x 128). grid = 64 blocks ----------------
__global__ __launch_bounds__(256) void gram_kernel(const float* __restrict__ x,
                                                   float* __restrict__ G, int M) {
  __shared__ float xL[128 * 132];
  const int t = threadIdx.x, tx = t & 15, ty = t >> 4;
  float acc[8][8] = {};
  const int rpb = M / gridDim.x;
  for (int r0 = blockIdx.x * rpb; r0 < blockIdx.x * rpb + rpb; r0 += 128) {
    __syncthreads();
#pragma unroll
    for (int i = 0; i < 16; ++i) {
      int f4 = t + i * 256;
      int r = f4 >> 5;
      int c4 = (f4 & 31) << 2;
      *(float4*)&xL[r * 132 + c4] = *(const float4*)&x[(size_t)(r0 + r) * 128 + c4];
    }
    __syncthreads();
    for (int r = 0; r < 128; ++r) {
      float4 a0 = *(const float4*)&xL[r * 132 + ty * 8];
      float4 a1 = *(const float4*)&xL[r * 132 + ty * 8 + 4];
      float4 b0 = *(const float4*)&xL[r * 132 + tx * 8];
      float4 b1 = *(const float4*)&xL[r * 132 + tx * 8 + 4];
      float a[8] = {a0.x, a0.y, a0.z, a0.w, a1.x, a1.y, a1.z, a1.w};
      float b[8] = {b0.x, b0.y, b0.z, b0.w, b1.x, b1.y, b1.z, b1.w};
#pragma unroll
      for (int i = 0; i < 8; ++i)
#pragma unroll
        for (int j = 0; j < 8; ++j) acc[i][j] += a[i] * b[j];
    }
  }
#pragma unroll
  for (int i = 0; i < 8; ++i)
#pragma unroll
    for (int j = 0; j < 8; ++j)
      atomicAdd(&G[(ty * 8 + i) * 128 + tx * 8 + j], acc[i][j]);
}

// ---------------- finalize layer-4 BN; emit BTf (fp16 fragment-major) + t4 ----------------
// BTf tile d (32KB): chunk f = (kout>>5)*8 + ks, lane = (kout&31)+lg*32, elems c = ks*16+lg*8+j
__global__ __launch_bounds__(256) void w4_finalize(const float* __restrict__ W4,
                                                   const float* __restrict__ U,
                                                   const float* __restrict__ colsum3,
                                                   const float* __restrict__ g4,
                                                   const float* __restrict__ b4,
                                                   _Float16* __restrict__ BTf,
                                                   float* __restrict__ t4,
                                                   float invM) {
  const int r = (blockIdx.x * 256 + threadIdx.x) >> 6;
  const int lane = threadIdx.x & 63;
  const float* wp = W4 + (size_t)r * 128;
  const float* up = U + (size_t)r * 128;
  float p1 = 0.f, p2 = 0.f;
#pragma unroll
  for (int c0 = 0; c0 < 128; c0 += 64) {
    float wv = wp[c0 + lane];
    p1 += up[c0 + lane] * wv;
    p2 += colsum3[c0 + lane] * wv;
  }
#pragma unroll
  for (int off = 32; off > 0; off >>= 1) {
    p1 += __shfl_down(p1, off);
    p2 += __shfl_down(p2, off);
  }
  p1 = __shfl(p1, 0);
  p2 = __shfl(p2, 0);
  float m4 = p2 * invM;
  float q = p1 * invM;
  float s = g4[r] * rsqrtf(q - m4 * m4 + EPS);
  if (lane == 0) t4[r] = b4[r] - m4 * s;
  const int kout = r & 127, d = r >> 7;
  if (lane < 16) {
    const int ks = lane >> 1, lg = lane & 1;
    const float* cp = wp + lane * 8;
    float4 va = *(const float4*)cp, vb = *(const float4*)(cp + 4);
    half8 h;
    h[0] = (_Float16)(s * va.x); h[1] = (_Float16)(s * va.y);
    h[2] = (_Float16)(s * va.z); h[3] = (_Float16)(s * va.w);
    h[4] = (_Float16)(s * vb.x); h[5] = (_Float16)(s * vb.y);
    h[6] = (_Float16)(s * vb.z); h[7] = (_Float16)(s * vb.w);
    size_t off16 = (size_t)d * 16384 +
                   (size_t)((((kout >> 5) * 8 + ks) * 64) + (kout & 31) + lg * 32) * 8;
    *(half8*)(BTf + off16) = h;
  }
}

// ---------------- msg = Z @ B via MFMA; A (=xi*x3) built in registers ----------------
// block 512 thr = 8 waves (4M x 2N of 64x64), tile 256M x 128N, KSPLIT=4 -> grid (4, 64).
__global__ __launch_bounds__(512) void zgemm(const float* __restrict__ x3,
                                             const float* __restrict__ node,
                                             const int* __restrict__ eidx,
                                             const _Float16* __restrict__ BTf,
                                             float* __restrict__ msg) {
  __shared__ _Float16 Bs[2][16384];   // 2 x 32KB, fragment-major
  __shared__ _Float16 xiL[32 * 256];  // [d][e] 16KB
  const int t = threadIdx.x;
  const int e0 = blockIdx.y * 256;
  const int d0 = blockIdx.x * 32;
  const int w = t >> 6, l = t & 63;
  const int wm = w >> 1, wn = w & 1;
  const int lr = l & 31, lg = l >> 5;
  // stage xiL[d][e]
  {
    const int e = t >> 1, db = (t & 1) * 16;
    const int src = eidx[(e0 + e) * 2];
    const float* np = node + (size_t)src * 128 + d0 + db;
#pragma unroll
    for (int j = 0; j < 16; j += 4) {
      float4 v = *(const float4*)(np + j);
      xiL[(db + j + 0) * 256 + e] = (_Float16)v.x;
      xiL[(db + j + 1) * 256 + e] = (_Float16)v.y;
      xiL[(db + j + 2) * 256 + e] = (_Float16)v.z;
      xiL[(db + j + 3) * 256 + e] = (_Float16)v.w;
    }
  }
  // x3 fragments -> registers (invariant across d-tiles)
  half8 xf0[8], xf1[8];
  {
    const float* xp0 = x3 + (size_t)(e0 + wm * 64 + lr) * 128 + lg * 8;
    const float* xp1 = x3 + (size_t)(e0 + wm * 64 + 32 + lr) * 128 + lg * 8;
#pragma unroll
    for (int ks = 0; ks < 8; ++ks) {
      float4 a = *(const float4*)(xp0 + ks * 16);
      float4 b = *(const float4*)(xp0 + ks * 16 + 4);
      half8 h;
      h[0] = (_Float16)a.x; h[1] = (_Float16)a.y; h[2] = (_Float16)a.z; h[3] = (_Float16)a.w;
      h[4] = (_Float16)b.x; h[5] = (_Float16)b.y; h[6] = (_Float16)b.z; h[7] = (_Float16)b.w;
      xf0[ks] = h;
      float4 c = *(const float4*)(xp1 + ks * 16);
      float4 d = *(const float4*)(xp1 + ks * 16 + 4);
      half8 h1;
      h1[0] = (_Float16)c.x; h1[1] = (_Float16)c.y; h1[2] = (_Float16)c.z; h1[3] = (_Float16)c.w;
      h1[4] = (_Float16)d.x; h1[5] = (_Float16)d.y; h1[6] = (_Float16)d.z; h1[7] = (_Float16)d.w;
      xf1[ks] = h1;
    }
  }
  f32x16 acc00 = (f32x16){0.f}, acc01 = (f32x16){0.f};
  f32x16 acc10 = (f32x16){0.f}, acc11 = (f32x16){0.f};
  // prologue: load B tile 0 into regs
  half8 st0, st1, st2, st3;
  {
    const _Float16* p = BTf + (size_t)d0 * 16384 + (size_t)t * 8;
    st0 = *(const half8*)(p);
    st1 = *(const half8*)(p + 4096);
    st2 = *(const half8*)(p + 8192);
    st3 = *(const half8*)(p + 12288);
  }
  __syncthreads();  // xiL visible
  for (int dt = 0; dt < 32; ++dt) {
    _Float16* bs = &Bs[dt & 1][0];
    *(half8*)(bs + t * 8) = st0;
    *(half8*)(bs + 4096 + t * 8) = st1;
    *(half8*)(bs + 8192 + t * 8) = st2;
    *(half8*)(bs + 12288 + t * 8) = st3;
    if (dt < 31) {
      const _Float16* p = BTf + (size_t)(d0 + dt + 1) * 16384 + (size_t)t * 8;
      st0 = *(const half8*)(p);
      st1 = *(const half8*)(p + 4096);
      st2 = *(const half8*)(p + 8192);
      st3 = *(const half8*)(p + 12288);
    }
    asm volatile("s_waitcnt lgkmcnt(0)" ::: "memory");
    __builtin_amdgcn_s_barrier();
    const _Float16 xv0 = xiL[dt * 256 + wm * 64 + lr];
    const _Float16 xv1 = xiL[dt * 256 + wm * 64 + 32 + lr];
    const half8 xb0 = {xv0, xv0, xv0, xv0, xv0, xv0, xv0, xv0};
    const half8 xb1 = {xv1, xv1, xv1, xv1, xv1, xv1, xv1, xv1};
#pragma unroll
    for (int ks = 0; ks < 8; ++ks) {
      half8 b0 = *(const half8*)(bs + (size_t)(((wn * 2 + 0) * 8 + ks) * 64 + l) * 8);
      half8 b1 = *(const half8*)(bs + (size_t)(((wn * 2 + 1) * 8 + ks) * 64 + l) * 8);
      half8 a0 = xf0[ks] * xb0;
      half8 a1 = xf1[ks] * xb1;
      acc00 = __builtin_amdgcn_mfma_f32_32x32x16_f16(a0, b0, acc00, 0, 0, 0);
      acc01 = __builtin_amdgcn_mfma_f32_32x32x16_f16(a0, b1, acc01, 0, 0, 0);
      acc10 = __builtin_amdgcn_mfma_f32_32x32x16_f16(a1, b0, acc10, 0, 0, 0);
      acc11 = __builtin_amdgcn_mfma_f32_32x32x16_f16(a1, b1, acc11, 0, 0, 0);
    }
  }
  // epilogue: split-K atomic accumulate
#pragma unroll
  for (int r = 0; r < 16; ++r) {
    const int rl = (r & 3) + 8 * (r >> 2) + 4 * lg;
    const int e_0 = e0 + wm * 64 + rl;
    const int e_1 = e_0 + 32;
    const int c0 = wn * 64 + lr;
    atomicAdd(&msg[(size_t)e_0 * 128 + c0], acc00[r]);
    atomicAdd(&msg[(size_t)e_0 * 128 + c0 + 32], acc01[r]);
    atomicAdd(&msg[(size_t)e_1 * 128 + c0], acc10[r]);
    atomicAdd(&msg[(size_t)e_1 * 128 + c0 + 32], acc11[r]);
  }
}

// ---------------- Tn = node @ t4mat ----------------
__global__ __launch_bounds__(128) void t4n_kernel(const float* __restrict__ node,
                                                  const float* __restrict__ t4,
                                                  float* __restrict__ Tn) {
  __shared__ float nodeL[8][128];
  const int k = threadIdx.x;
  const int n0 = blockIdx.x * 8;
#pragma unroll
  for (int j = 0; j < 8; ++j) nodeL[j][k] = node[(size_t)(n0 + j) * 128 + k];
  __syncthreads();
  float acc[8] = {};
  for (int d = 0; d < 128; ++d) {
    float wv = t4[d * 128 + k];
#pragma unroll
    for (int j = 0; j < 8; ++j) acc[j] += nodeL[j][d] * wv;
  }
#pragma unroll
  for (int j = 0; j < 8; ++j) Tn[(size_t)(n0 + j) * 128 + k] = acc[j];
}

// ---------------- segment sum (atomics), msg + Tn[src] gathered ----------------
__global__ __launch_bounds__(256) void scatter_add(const float* __restrict__ msg,
                                                   const float* __restrict__ Tn,
                                                   const int* __restrict__ eidx,
                                                   float* __restrict__ sums, int E) {
  int idx = blockIdx.x * 256 + threadIdx.x;
  if (idx >= E * 128) return;
  int e = idx >> 7, k = idx & 127;
  int src = eidx[e * 2 + 0];
  int dstn = eidx[e * 2 + 1];
  atomicAdd(&sums[(size_t)dstn * 128 + k], msg[idx] + Tn[(size_t)src * 128 + k]);
}

__global__ __launch_bounds__(256) void cnt_kernel(const int* __restrict__ eidx,
                                                  float* __restrict__ cnt, int E) {
  int e = blockIdx.x * 256 + threadIdx.x;
  if (e < E) atomicAdd(&cnt[eidx[e * 2 + 1]], 1.0f);
}

// ---------------- m = relu(sums/max(cnt,1) + bias) ----------------
__global__ __launch_bounds__(256) void mrelu_kernel(const float* __restrict__ sums,
                                                    const float* __restrict__ cnt,
                                                    const float* __restrict__ bias,
                                                    float* __restrict__ m) {
  int idx = blockIdx.x * 256 + threadIdx.x;
  int n = idx >> 7, k = idx & 127;
  float v = sums[idx] / fmaxf(cnt[n], 1.0f) + bias[k];
  m[idx] = fmaxf(v, 0.f);
}

// ---------------- GRU gate finalize ----------------
__global__ __launch_bounds__(256) void gru_finalize(const float* __restrict__ gi,
                                                    const float* __restrict__ gh,
                                                    const float* __restrict__ h0,
                                                    const float* __restrict__ bih,
                                                    const float* __restrict__ bhh,
                                                    float* __restrict__ out, int Nn) {
  int idx = blockIdx.x * 256 + threadIdx.x;
  int n = idx >> 7, k = idx & 127;
  const float* gin = gi + (size_t)n * 384;
  const float* ghn = gh + (size_t)n * 384;
  float r = 1.f / (1.f + expf(-(gin[k] + bih[k] + ghn[k] + bhh[k])));
  float z = 1.f / (1.f + expf(-(gin[128 + k] + bih[128 + k] + ghn[128 + k] + bhh[128 + k])));
  float nn = tanhf(gin[256 + k] + bih[256 + k] + r * (ghn[256 + k] + bhh[256 + k]));
  float h = h0[idx];
  float hn = (1.f - z) * nn + z * h;
  out[idx] = hn;
  out[idx + (size_t)Nn * 128] = hn;
}

extern "C" void kernel_launch(void* const* d_in, const int* in_sizes, int n_in,
                              void* d_out, int out_size, void* d_ws, size_t ws_size,
                              hipStream_t stream) {
  const float* node = (const float*)d_in[0];
  const int* eidx = (const int*)d_in[1];
  const float* edge = (const float*)d_in[2];
  const float* hidden = (const float*)d_in[3];
  const float* W1 = (const float*)d_in[4];
  const float* g1 = (const float*)d_in[5];
  const float* b1 = (const float*)d_in[6];
  const float* W2 = (const float*)d_in[7];
  const float* g2 = (const float*)d_in[8];
  const float* b2 = (const float*)d_in[9];
  const float* W3 = (const float*)d_in[10];
  const float* g3 = (const float*)d_in[11];
  const float* b3 = (const float*)d_in[12];
  const float* W4 = (const float*)d_in[13];
  const float* g4 = (const float*)d_in[14];
  const float* b4 = (const float*)d_in[15];
  const float* bias = (const float*)d_in[16];
  const float* Wih = (const float*)d_in[17];
  const float* Whh = (const float*)d_in[18];
  const float* bih = (const float*)d_in[19];
  const float* bhh = (const float*)d_in[20];
  float* out = (float*)d_out;

  const int Nn = in_sizes[0] / 128;   // 4096
  const int E = in_sizes[2] / 16;     // 16384

  float* ws = (float*)d_ws;
  float* ybuf1 = ws + 0;                       // E x 256 (x1; later msg Ex128)
  float* ybuf2 = ws + 4194304;                 // E x 256 (x2; later U; later gi/gh)
  float* x3 = ws + 8388608;                    // E x 128
  _Float16* BTf = (_Float16*)(ws + 10485760);  // 128 tiles x 16384 halves (4MB)
  float* t4 = ws + 11534336;                   // 16384
  float* stat = ws + 11550720;                 // 512
  float* G3 = ws + 11551232;                   // 128 x 128
  float* sums = ws + 11567616;                 // Nn x 128
  float* cnt = ws + 12091904;                  // Nn
  float* mrow = ws + 12096000;                 // Nn x 128
  float* Tn = ws + 12620288;                   // Nn x 128
  float* gi = ybuf2;                           // 4096 x 384
  float* gh = ybuf2 + 1572864;                 // 4096 x 384

  // ---- layer 1: y1 = edge @ W1^T ; BN+relu ----
  gemm_abt<<<dim3(256 / 64, E / 64), 256, 0, stream>>>(edge, W1, ybuf1, E, 256, 16);
  hipMemsetAsync(stat, 0, 512 * sizeof(float), stream);
  colstats<<<128, 256, 0, stream>>>(ybuf1, stat, stat + 256, E, 256);
  bn_apply<<<E * 256 / 256, 256, 0, stream>>>(ybuf1, stat, stat + 256, g1, b1, E, 256, 1);

  // ---- layer 2 (MFMA) ----
  gemm16<<<dim3(2, E / 128), 256, 0, stream>>>(ybuf1, W2, ybuf2, 256, 256, 256, 256);
  hipMemsetAsync(stat, 0, 512 * sizeof(float), stream);
  colstats<<<128, 256, 0, stream>>>(ybuf2, stat, stat + 256, E, 256);
  bn_apply<<<E * 256 / 256, 256, 0, stream>>>(ybuf2, stat, stat + 256, g2, b2, E, 256, 1);

  // ---- layer 3 (MFMA) ----
  gemm16<<<dim3(1, E / 128), 256, 0, stream>>>(ybuf2, W3, x3, 256, 256, 128, 256);
  hipMemsetAsync(stat, 0, 512 * sizeof(float), stream);
  colstats<<<128, 256, 0, stream>>>(x3, stat, stat + 256, E, 128);
  bn_apply<<<E * 128 / 256, 256, 0, stream>>>(x3, stat, stat + 256, g3, b3, E, 128, 1);

  // ---- layer-4 BN stats via Gram trick; emit BTf fp16 + t4 ----
  hipMemsetAsync(stat, 0, 512 * sizeof(float), stream);
  colstats<<<128, 256, 0, stream>>>(x3, stat, stat + 256, E, 128);       // colsum3
  hipMemsetAsync(G3, 0, 16384 * sizeof(float), stream);
  gram_kernel<<<64, 256, 0, stream>>>(x3, G3, E);
  gemm16<<<dim3(1, 16384 / 128), 256, 0, stream>>>(W4, G3, ybuf2, 128, 128, 128, 128);  // U
  w4_finalize<<<16384 / 4, 256, 0, stream>>>(W4, ybuf2, stat, g4, b4, BTf, t4,
                                             1.0f / (float)E);

  // ---- fused message GEMM (split-K=4, atomic f32) ----
  hipMemsetAsync(ybuf1, 0, (size_t)E * 128 * sizeof(float), stream);
  zgemm<<<dim3(4, E / 256), 512, 0, stream>>>(x3, node, eidx, BTf, ybuf1);
  t4n_kernel<<<Nn / 8, 128, 0, stream>>>(node, t4, Tn);

  // ---- segment mean ----
  hipMemsetAsync(sums, 0, (size_t)Nn * 128 * sizeof(float), stream);
  hipMemsetAsync(cnt, 0, (size_t)Nn * sizeof(float), stream);
  scatter_add<<<E * 128 / 256, 256, 0, stream>>>(ybuf1, Tn, eidx, sums, E);
  cnt_kernel<<<(E + 255) / 256, 256, 0, stream>>>(eidx, cnt, E);
  mrelu_kernel<<<Nn * 128 / 256, 256, 0, stream>>>(sums, cnt, bias, mrow);

  // ---- GRU (MFMA gates + finalize) ----
  gemm16<<<dim3(3, Nn / 128), 256, 0, stream>>>(mrow, Wih, gi, 128, 128, 384, 128);
  gemm16<<<dim3(3, Nn / 128), 256, 0, stream>>>(hidden, Whh, gh, 128, 128, 384, 128);
  gru_finalize<<<Nn * 128 / 256, 256, 0, stream>>>(gi, gh, hidden, bih, bhh, out, Nn);
}

// Round 4
// 235.761 us; speedup vs baseline: 16.6040x; 1.7019x over previous
//
#include <hip/hip_runtime.h>

#define EPS 1e-5f

typedef _Float16 half8 __attribute__((ext_vector_type(8)));
typedef float f32x16 __attribute__((ext_vector_type(16)));

__device__ __forceinline__ float dot4(float4 a, float4 b) {
  return a.x * b.x + a.y * b.y + a.z * b.z + a.w * b.w;
}

// ---------------- L1: C = A(Mx16) @ B(Nx16)^T, f32, + col-stats epilogue ----------------
__global__ __launch_bounds__(256) void gemm_abt(const float* __restrict__ A,
                                                const float* __restrict__ B,
                                                float* __restrict__ C,
                                                int M, int N, int K,
                                                float* __restrict__ osum,
                                                float* __restrict__ osq) {
  __shared__ float As[16][68];
  __shared__ float Bs[16][68];
  const int t = threadIdx.x;
  const int tx = t & 15, ty = t >> 4;
  const int m0 = blockIdx.y * 64, n0 = blockIdx.x * 64;
  float acc[4][4] = {};
  for (int k0 = 0; k0 < K; k0 += 16) {
    __syncthreads();
    {
      const int r = t >> 2;
      const int kk = (t & 3) << 2;
      float4 av = *(const float4*)&A[(size_t)(m0 + r) * K + k0 + kk];
      As[kk + 0][r] = av.x; As[kk + 1][r] = av.y;
      As[kk + 2][r] = av.z; As[kk + 3][r] = av.w;
      float4 bv = *(const float4*)&B[(size_t)(n0 + r) * K + k0 + kk];
      Bs[kk + 0][r] = bv.x; Bs[kk + 1][r] = bv.y;
      Bs[kk + 2][r] = bv.z; Bs[kk + 3][r] = bv.w;
    }
    __syncthreads();
#pragma unroll
    for (int kk = 0; kk < 16; ++kk) {
      float4 a = *(const float4*)&As[kk][ty << 2];
      float4 b = *(const float4*)&Bs[kk][tx << 2];
      float av[4] = {a.x, a.y, a.z, a.w};
      float bv[4] = {b.x, b.y, b.z, b.w};
#pragma unroll
      for (int i = 0; i < 4; ++i)
#pragma unroll
        for (int j = 0; j < 4; ++j) acc[i][j] += av[i] * bv[j];
    }
  }
#pragma unroll
  for (int i = 0; i < 4; ++i) {
    float4 o = make_float4(acc[i][0], acc[i][1], acc[i][2], acc[i][3]);
    *(float4*)&C[(size_t)(m0 + (ty << 2) + i) * N + n0 + (tx << 2)] = o;
  }
  // ---- col-stats: LDS reduce then 2 atomics/col ----
  __syncthreads();
  float* sred = (float*)As;  // 128 floats
  if (t < 128) sred[t] = 0.f;
  __syncthreads();
#pragma unroll
  for (int j = 0; j < 4; ++j) {
    float s = 0.f, sq = 0.f;
#pragma unroll
    for (int i = 0; i < 4; ++i) {
      float v = acc[i][j];
      s += v; sq += v * v;
    }
    atomicAdd(&sred[((tx << 2) + j) * 2 + 0], s);
    atomicAdd(&sred[((tx << 2) + j) * 2 + 1], sq);
  }
  __syncthreads();
  if (t < 64) {
    atomicAdd(&osum[n0 + t], sred[t * 2]);
    atomicAdd(&osq[n0 + t], sred[t * 2 + 1]);
  }
}

// ---------------- MFMA fp16 GEMM: C(f32) = T(A) @ B^T ----------------
// TRANS: 0 none, 1 BN(stat s1,s2 over K-cols; g,b; relu), 2 mrelu(cnt per row, bias per k).
// STATS: accumulate col sum/sumsq of C into osum/osq.
template <int TRANS, bool STATS>
__global__ __launch_bounds__(256) void gemm16(const float* __restrict__ A,
                                              const float* __restrict__ B,
                                              float* __restrict__ C,
                                              int lda, int ldb, int ldc, int K,
                                              const float* __restrict__ s1,
                                              const float* __restrict__ s2,
                                              const float* __restrict__ g,
                                              const float* __restrict__ b,
                                              float invM,
                                              float* __restrict__ osum,
                                              float* __restrict__ osq) {
  __shared__ _Float16 As[128 * 64];
  __shared__ _Float16 Bs[128 * 64];
  __shared__ float scL[256], shL[256];
  const int t = threadIdx.x;
  const int m0 = blockIdx.y * 128, n0 = blockIdx.x * 128;
  const int w = t >> 6, l = t & 63;
  const int wm = w >> 1, wn = w & 1;
  const int lr = l & 31, lg = l >> 5;
  if (TRANS == 1) {
    if (t < K) {
      float mean = s1[t] * invM;
      float var = s2[t] * invM - mean * mean;
      float sc = g[t] * rsqrtf(var + EPS);
      scL[t] = sc;
      shL[t] = b[t] - mean * sc;
    }
  }
  f32x16 acc[2][2];
#pragma unroll
  for (int i = 0; i < 2; ++i)
#pragma unroll
    for (int j = 0; j < 2; ++j) acc[i][j] = (f32x16){0.f};
  for (int k0 = 0; k0 < K; k0 += 64) {
    __syncthreads();
#pragma unroll
    for (int i = 0; i < 4; ++i) {
      const int gq = i * 256 + t;
      const int f = gq >> 6, lp = gq & 63;
      const int row = (f >> 2) * 32 + (lp & 31);
      const int c = (f & 3) * 16 + (lp >> 5) * 8;
      const float* ap = A + (size_t)(m0 + row) * lda + k0 + c;
      float4 a4 = *(const float4*)ap, b4 = *(const float4*)(ap + 4);
      float va[8] = {a4.x, a4.y, a4.z, a4.w, b4.x, b4.y, b4.z, b4.w};
      if (TRANS == 1) {
#pragma unroll
        for (int j = 0; j < 8; ++j)
          va[j] = fmaxf(va[j] * scL[k0 + c + j] + shL[k0 + c + j], 0.f);
      } else if (TRANS == 2) {
        float rc = 1.f / fmaxf(s1[m0 + row], 1.f);
#pragma unroll
        for (int j = 0; j < 8; ++j) va[j] = fmaxf(va[j] * rc + s2[k0 + c + j], 0.f);
      }
      half8 h;
#pragma unroll
      for (int j = 0; j < 8; ++j) h[j] = (_Float16)va[j];
      *(half8*)(As + (size_t)gq * 8) = h;
      const float* bp = B + (size_t)(n0 + row) * ldb + k0 + c;
      float4 e4 = *(const float4*)bp, f4 = *(const float4*)(bp + 4);
      half8 hb;
      hb[0] = (_Float16)e4.x; hb[1] = (_Float16)e4.y; hb[2] = (_Float16)e4.z; hb[3] = (_Float16)e4.w;
      hb[4] = (_Float16)f4.x; hb[5] = (_Float16)f4.y; hb[6] = (_Float16)f4.z; hb[7] = (_Float16)f4.w;
      *(half8*)(Bs + (size_t)gq * 8) = hb;
    }
    __syncthreads();
#pragma unroll
    for (int ks = 0; ks < 4; ++ks) {
      half8 af[2], bf[2];
#pragma unroll
      for (int mb = 0; mb < 2; ++mb) {
        const int fa = ((wm * 2 + mb) * 4 + ks);
        af[mb] = *(const half8*)(As + (size_t)(fa * 64 + l) * 8);
        const int fb = ((wn * 2 + mb) * 4 + ks);
        bf[mb] = *(const half8*)(Bs + (size_t)(fb * 64 + l) * 8);
      }
#pragma unroll
      for (int mb = 0; mb < 2; ++mb)
#pragma unroll
        for (int nb = 0; nb < 2; ++nb)
          acc[mb][nb] = __builtin_amdgcn_mfma_f32_32x32x16_f16(af[mb], bf[nb], acc[mb][nb], 0, 0, 0);
    }
  }
#pragma unroll
  for (int mb = 0; mb < 2; ++mb)
#pragma unroll
    for (int nb = 0; nb < 2; ++nb)
#pragma unroll
      for (int r = 0; r < 16; ++r) {
        const int row = m0 + wm * 64 + mb * 32 + (r & 3) + 8 * (r >> 2) + 4 * lg;
        const int col = n0 + wn * 64 + nb * 32 + lr;
        C[(size_t)row * ldc + col] = acc[mb][nb][r];
      }
  if (STATS) {
    __syncthreads();
    float* sred = (float*)As;  // 256 floats
    if (t < 256) sred[t] = 0.f;
    __syncthreads();
#pragma unroll
    for (int nb = 0; nb < 2; ++nb) {
      float s = 0.f, sq = 0.f;
#pragma unroll
      for (int mb = 0; mb < 2; ++mb)
#pragma unroll
        for (int r = 0; r < 16; ++r) {
          float v = acc[mb][nb][r];
          s += v; sq += v * v;
        }
      const int cl = wn * 64 + nb * 32 + lr;
      atomicAdd(&sred[cl * 2 + 0], s);
      atomicAdd(&sred[cl * 2 + 1], sq);
    }
    __syncthreads();
    if (t < 128) {
      atomicAdd(&osum[n0 + t], sred[t * 2]);
      atomicAdd(&osq[n0 + t], sred[t * 2 + 1]);
    }
  }
}

// ---------------- BN apply (+relu), in place (layer 3 only) ----------------
__global__ __launch_bounds__(256) void bn_apply(float* __restrict__ y,
                                                const float* __restrict__ colsum,
                                                const float* __restrict__ colsumsq,
                                                const float* __restrict__ g,
                                                const float* __restrict__ b,
                                                int M, int N) {
  const int idx = blockIdx.x * 256 + threadIdx.x;
  const int col = idx % N;
  const float invM = 1.0f / (float)M;
  float mean = colsum[col] * invM;
  float var = colsumsq[col] * invM - mean * mean;
  float v = (y[idx] - mean) * rsqrtf(var + EPS) * g[col] + b[col];
  y[idx] = fmaxf(v, 0.f);
}

// ---------------- Gram partials: 128 blocks; also diag col-sums ----------------
__global__ __launch_bounds__(256) void gram_kernel(const float* __restrict__ x,
                                                   float* __restrict__ part, int M) {
  __shared__ float xL[128 * 132];
  const int t = threadIdx.x, tx = t & 15, ty = t >> 4;
  float acc[8][8] = {};
  float csum[8] = {};
  const int rpb = M / gridDim.x;  // 128
  for (int r0 = blockIdx.x * rpb; r0 < blockIdx.x * rpb + rpb; r0 += 128) {
    __syncthreads();
#pragma unroll
    for (int i = 0; i < 16; ++i) {
      int f4 = t + i * 256;
      int r = f4 >> 5;
      int c4 = (f4 & 31) << 2;
      *(float4*)&xL[r * 132 + c4] = *(const float4*)&x[(size_t)(r0 + r) * 128 + c4];
    }
    __syncthreads();
    for (int r = 0; r < 128; ++r) {
      float4 a0 = *(const float4*)&xL[r * 132 + ty * 8];
      float4 a1 = *(const float4*)&xL[r * 132 + ty * 8 + 4];
      float4 b0 = *(const float4*)&xL[r * 132 + tx * 8];
      float4 b1 = *(const float4*)&xL[r * 132 + tx * 8 + 4];
      float a[8] = {a0.x, a0.y, a0.z, a0.w, a1.x, a1.y, a1.z, a1.w};
      float b[8] = {b0.x, b0.y, b0.z, b0.w, b1.x, b1.y, b1.z, b1.w};
#pragma unroll
      for (int i = 0; i < 8; ++i)
#pragma unroll
        for (int j = 0; j < 8; ++j) acc[i][j] += a[i] * b[j];
      if (tx == ty) {
#pragma unroll
        for (int i = 0; i < 8; ++i) csum[i] += a[i];
      }
    }
  }
  float* base = part + (size_t)blockIdx.x * 16512;
#pragma unroll
  for (int i = 0; i < 8; ++i)
#pragma unroll
    for (int j = 0; j < 8; ++j)
      base[(ty * 8 + i) * 128 + tx * 8 + j] = acc[i][j];
  if (tx == ty) {
#pragma unroll
    for (int i = 0; i < 8; ++i) base[16384 + ty * 8 + i] = csum[i];
  }
}

__global__ __launch_bounds__(256) void gram_reduce(const float* __restrict__ part,
                                                   float* __restrict__ out) {
  int idx = blockIdx.x * 256 + threadIdx.x;
  if (idx >= 16512) return;
  float s = 0.f;
  for (int b = 0; b < 128; ++b) s += part[(size_t)b * 16512 + idx];
  out[idx] = s;
}

// ---------------- finalize layer-4 BN; emit BTf (fp16 fragment-major) + t4 ----------------
__global__ __launch_bounds__(256) void w4_finalize(const float* __restrict__ W4,
                                                   const float* __restrict__ U,
                                                   const float* __restrict__ colsum3,
                                                   const float* __restrict__ g4,
                                                   const float* __restrict__ b4,
                                                   _Float16* __restrict__ BTf,
                                                   float* __restrict__ t4,
                                                   float invM) {
  const int r = (blockIdx.x * 256 + threadIdx.x) >> 6;
  const int lane = threadIdx.x & 63;
  const float* wp = W4 + (size_t)r * 128;
  const float* up = U + (size_t)r * 128;
  float p1 = 0.f, p2 = 0.f;
#pragma unroll
  for (int c0 = 0; c0 < 128; c0 += 64) {
    float wv = wp[c0 + lane];
    p1 += up[c0 + lane] * wv;
    p2 += colsum3[c0 + lane] * wv;
  }
#pragma unroll
  for (int off = 32; off > 0; off >>= 1) {
    p1 += __shfl_down(p1, off);
    p2 += __shfl_down(p2, off);
  }
  p1 = __shfl(p1, 0);
  p2 = __shfl(p2, 0);
  float m4 = p2 * invM;
  float q = p1 * invM;
  float s = g4[r] * rsqrtf(q - m4 * m4 + EPS);
  if (lane == 0) t4[r] = b4[r] - m4 * s;
  const int kout = r & 127, d = r >> 7;
  if (lane < 16) {
    const int ks = lane >> 1, lg = lane & 1;
    const float* cp = wp + lane * 8;
    float4 va = *(const float4*)cp, vb = *(const float4*)(cp + 4);
    half8 h;
    h[0] = (_Float16)(s * va.x); h[1] = (_Float16)(s * va.y);
    h[2] = (_Float16)(s * va.z); h[3] = (_Float16)(s * va.w);
    h[4] = (_Float16)(s * vb.x); h[5] = (_Float16)(s * vb.y);
    h[6] = (_Float16)(s * vb.z); h[7] = (_Float16)(s * vb.w);
    size_t off16 = (size_t)d * 16384 +
                   (size_t)((((kout >> 5) * 8 + ks) * 64) + (kout & 31) + lg * 32) * 8;
    *(half8*)(BTf + off16) = h;
  }
}

// ---------------- zgemm: direct-scatter message GEMM ----------------
// 4 waves (2M x 2N of 64x64), tile 128e x 128n, KSPLIT=4 -> grid (4, E/128).
// Epilogue: atomicAdd into sums[dst[e]]; split 0 adds Tn[src[e]].
__global__ __launch_bounds__(256, 2) void zgemm(const float* __restrict__ x3,
                                                const float* __restrict__ node,
                                                const int* __restrict__ eidx,
                                                const _Float16* __restrict__ BTf,
                                                const float* __restrict__ Tn,
                                                float* __restrict__ sums) {
  __shared__ _Float16 Bs[2][16384];   // 2 x 32KB fragment-major
  __shared__ _Float16 xiL[32 * 128];  // [d][e] 8KB
  const int t = threadIdx.x;
  const int e0 = blockIdx.y * 128;
  const int d0 = blockIdx.x * 32;
  const int w = t >> 6, l = t & 63;
  const int wm = w >> 1, wn = w & 1;
  const int lr = l & 31, lg = l >> 5;
  // stage xiL[d][e]
  {
    const int e = t >> 1, db = (t & 1) * 16;
    const int src = eidx[(e0 + e) * 2];
    const float* np = node + (size_t)src * 128 + d0 + db;
#pragma unroll
    for (int j = 0; j < 16; j += 4) {
      float4 v = *(const float4*)(np + j);
      xiL[(db + j + 0) * 128 + e] = (_Float16)v.x;
      xiL[(db + j + 1) * 128 + e] = (_Float16)v.y;
      xiL[(db + j + 2) * 128 + e] = (_Float16)v.z;
      xiL[(db + j + 3) * 128 + e] = (_Float16)v.w;
    }
  }
  // x3 fragments -> regs (invariant across d-tiles)
  half8 xf[2][8];
#pragma unroll
  for (int mb = 0; mb < 2; ++mb) {
    const float* xp = x3 + (size_t)(e0 + wm * 64 + mb * 32 + lr) * 128 + lg * 8;
#pragma unroll
    for (int ks = 0; ks < 8; ++ks) {
      float4 a = *(const float4*)(xp + ks * 16);
      float4 b = *(const float4*)(xp + ks * 16 + 4);
      half8 h;
      h[0] = (_Float16)a.x; h[1] = (_Float16)a.y; h[2] = (_Float16)a.z; h[3] = (_Float16)a.w;
      h[4] = (_Float16)b.x; h[5] = (_Float16)b.y; h[6] = (_Float16)b.z; h[7] = (_Float16)b.w;
      xf[mb][ks] = h;
    }
  }
  f32x16 acc00 = (f32x16){0.f}, acc01 = (f32x16){0.f};
  f32x16 acc10 = (f32x16){0.f}, acc11 = (f32x16){0.f};
  half8 st[8];
  {
    const _Float16* p = BTf + (size_t)d0 * 16384 + (size_t)t * 8;
#pragma unroll
    for (int j = 0; j < 8; ++j) st[j] = *(const half8*)(p + j * 2048);
  }
  __syncthreads();  // xiL visible
  for (int dt = 0; dt < 32; ++dt) {
    _Float16* bs = &Bs[dt & 1][0];
#pragma unroll
    for (int j = 0; j < 8; ++j) *(half8*)(bs + t * 8 + j * 2048) = st[j];
    if (dt < 31) {
      const _Float16* p = BTf + (size_t)(d0 + dt + 1) * 16384 + (size_t)t * 8;
#pragma unroll
      for (int j = 0; j < 8; ++j) st[j] = *(const half8*)(p + j * 2048);
    }
    asm volatile("s_waitcnt lgkmcnt(0)" ::: "memory");
    __builtin_amdgcn_s_barrier();
    const _Float16 xv0 = xiL[dt * 128 + wm * 64 + lr];
    const _Float16 xv1 = xiL[dt * 128 + wm * 64 + 32 + lr];
    const half8 xb0 = {xv0, xv0, xv0, xv0, xv0, xv0, xv0, xv0};
    const half8 xb1 = {xv1, xv1, xv1, xv1, xv1, xv1, xv1, xv1};
#pragma unroll
    for (int ks = 0; ks < 8; ++ks) {
      half8 b0 = *(const half8*)(bs + (size_t)(((wn * 2 + 0) * 8 + ks) * 64 + l) * 8);
      half8 b1 = *(const half8*)(bs + (size_t)(((wn * 2 + 1) * 8 + ks) * 64 + l) * 8);
      half8 a0 = xf[0][ks] * xb0;
      half8 a1 = xf[1][ks] * xb1;
      acc00 = __builtin_amdgcn_mfma_f32_32x32x16_f16(a0, b0, acc00, 0, 0, 0);
      acc01 = __builtin_amdgcn_mfma_f32_32x32x16_f16(a0, b1, acc01, 0, 0, 0);
      acc10 = __builtin_amdgcn_mfma_f32_32x32x16_f16(a1, b0, acc10, 0, 0, 0);
      acc11 = __builtin_amdgcn_mfma_f32_32x32x16_f16(a1, b1, acc11, 0, 0, 0);
    }
  }
  // epilogue: direct scatter into sums; split 0 adds Tn[src]
  const bool add_t = (blockIdx.x == 0);
#pragma unroll
  for (int r = 0; r < 16; ++r) {
    const int rl = (r & 3) + 8 * (r >> 2) + 4 * lg;
    const int eA = e0 + wm * 64 + rl;
    const int eB = eA + 32;
    const int dA = eidx[eA * 2 + 1], sA = eidx[eA * 2];
    const int dB = eidx[eB * 2 + 1], sB = eidx[eB * 2];
    const int c0 = wn * 64 + lr;
    float v00 = acc00[r], v01 = acc01[r], v10 = acc10[r], v11 = acc11[r];
    if (add_t) {
      v00 += Tn[(size_t)sA * 128 + c0];
      v01 += Tn[(size_t)sA * 128 + c0 + 32];
      v10 += Tn[(size_t)sB * 128 + c0];
      v11 += Tn[(size_t)sB * 128 + c0 + 32];
    }
    atomicAdd(&sums[(size_t)dA * 128 + c0], v00);
    atomicAdd(&sums[(size_t)dA * 128 + c0 + 32], v01);
    atomicAdd(&sums[(size_t)dB * 128 + c0], v10);
    atomicAdd(&sums[(size_t)dB * 128 + c0 + 32], v11);
  }
}

// ---------------- Tn = node @ t4mat ----------------
__global__ __launch_bounds__(128) void t4n_kernel(const float* __restrict__ node,
                                                  const float* __restrict__ t4,
                                                  float* __restrict__ Tn) {
  __shared__ float nodeL[8][128];
  const int k = threadIdx.x;
  const int n0 = blockIdx.x * 8;
#pragma unroll
  for (int j = 0; j < 8; ++j) nodeL[j][k] = node[(size_t)(n0 + j) * 128 + k];
  __syncthreads();
  float acc[8] = {};
  for (int d = 0; d < 128; ++d) {
    float wv = t4[d * 128 + k];
#pragma unroll
    for (int j = 0; j < 8; ++j) acc[j] += nodeL[j][d] * wv;
  }
#pragma unroll
  for (int j = 0; j < 8; ++j) Tn[(size_t)(n0 + j) * 128 + k] = acc[j];
}

__global__ __launch_bounds__(256) void cnt_kernel(const int* __restrict__ eidx,
                                                  float* __restrict__ cnt, int E) {
  int e = blockIdx.x * 256 + threadIdx.x;
  if (e < E) atomicAdd(&cnt[eidx[e * 2 + 1]], 1.0f);
}

// ---------------- GRU gates: one dispatch; bx<3 -> gi (mrelu A), else gh ----------------
__global__ __launch_bounds__(256) void gru_gates(const float* __restrict__ sums,
                                                 const float* __restrict__ cnt,
                                                 const float* __restrict__ bias,
                                                 const float* __restrict__ h0,
                                                 const float* __restrict__ Wih,
                                                 const float* __restrict__ Whh,
                                                 float* __restrict__ gi,
                                                 float* __restrict__ gh) {
  __shared__ _Float16 As[128 * 64];
  __shared__ _Float16 Bs[128 * 64];
  const bool isgh = blockIdx.x >= 3;
  const float* A = isgh ? h0 : sums;
  const float* B = isgh ? Whh : Wih;
  float* C = isgh ? gh : gi;
  const int n0 = (isgh ? blockIdx.x - 3 : blockIdx.x) * 128;
  const int m0 = blockIdx.y * 128;
  const int t = threadIdx.x;
  const int w = t >> 6, l = t & 63;
  const int wm = w >> 1, wn = w & 1;
  const int lr = l & 31, lg = l >> 5;
  f32x16 acc[2][2];
#pragma unroll
  for (int i = 0; i < 2; ++i)
#pragma unroll
    for (int j = 0; j < 2; ++j) acc[i][j] = (f32x16){0.f};
  for (int k0 = 0; k0 < 128; k0 += 64) {
    __syncthreads();
#pragma unroll
    for (int i = 0; i < 4; ++i) {
      const int gq = i * 256 + t;
      const int f = gq >> 6, lp = gq & 63;
      const int row = (f >> 2) * 32 + (lp & 31);
      const int c = (f & 3) * 16 + (lp >> 5) * 8;
      const float* ap = A + (size_t)(m0 + row) * 128 + k0 + c;
      float4 a4 = *(const float4*)ap, b4 = *(const float4*)(ap + 4);
      float va[8] = {a4.x, a4.y, a4.z, a4.w, b4.x, b4.y, b4.z, b4.w};
      if (!isgh) {
        float rc = 1.f / fmaxf(cnt[m0 + row], 1.f);
#pragma unroll
        for (int j = 0; j < 8; ++j) va[j] = fmaxf(va[j] * rc + bias[k0 + c + j], 0.f);
      }
      half8 h;
#pragma unroll
      for (int j = 0; j < 8; ++j) h[j] = (_Float16)va[j];
      *(half8*)(As + (size_t)gq * 8) = h;
      const float* bp = B + (size_t)(n0 + row) * 128 + k0 + c;
      float4 e4 = *(const float4*)bp, f4 = *(const float4*)(bp + 4);
      half8 hb;
      hb[0] = (_Float16)e4.x; hb[1] = (_Float16)e4.y; hb[2] = (_Float16)e4.z; hb[3] = (_Float16)e4.w;
      hb[4] = (_Float16)f4.x; hb[5] = (_Float16)f4.y; hb[6] = (_Float16)f4.z; hb[7] = (_Float16)f4.w;
      *(half8*)(Bs + (size_t)gq * 8) = hb;
    }
    __syncthreads();
#pragma unroll
    for (int ks = 0; ks < 4; ++ks) {
      half8 af[2], bf[2];
#pragma unroll
      for (int mb = 0; mb < 2; ++mb) {
        af[mb] = *(const half8*)(As + (size_t)(((wm * 2 + mb) * 4 + ks) * 64 + l) * 8);
        bf[mb] = *(const half8*)(Bs + (size_t)(((wn * 2 + mb) * 4 + ks) * 64 + l) * 8);
      }
#pragma unroll
      for (int mb = 0; mb < 2; ++mb)
#pragma unroll
        for (int nb = 0; nb < 2; ++nb)
          acc[mb][nb] = __builtin_amdgcn_mfma_f32_32x32x16_f16(af[mb], bf[nb], acc[mb][nb], 0, 0, 0);
    }
  }
#pragma unroll
  for (int mb = 0; mb < 2; ++mb)
#pragma unroll
    for (int nb = 0; nb < 2; ++nb)
#pragma unroll
      for (int r = 0; r < 16; ++r) {
        const int row = m0 + wm * 64 + mb * 32 + (r & 3) + 8 * (r >> 2) + 4 * lg;
        const int col = n0 + wn * 64 + nb * 32 + lr;
        C[(size_t)row * 384 + col] = acc[mb][nb][r];
      }
}

// ---------------- GRU finalize ----------------
__global__ __launch_bounds__(256) void gru_finalize(const float* __restrict__ gi,
                                                    const float* __restrict__ gh,
                                                    const float* __restrict__ h0,
                                                    const float* __restrict__ bih,
                                                    const float* __restrict__ bhh,
                                                    float* __restrict__ out, int Nn) {
  int idx = blockIdx.x * 256 + threadIdx.x;
  int n = idx >> 7, k = idx & 127;
  const float* gin = gi + (size_t)n * 384;
  const float* ghn = gh + (size_t)n * 384;
  float r = 1.f / (1.f + expf(-(gin[k] + bih[k] + ghn[k] + bhh[k])));
  float z = 1.f / (1.f + expf(-(gin[128 + k] + bih[128 + k] + ghn[128 + k] + bhh[128 + k])));
  float nn = tanhf(gin[256 + k] + bih[256 + k] + r * (ghn[256 + k] + bhh[256 + k]));
  float h = h0[idx];
  float hn = (1.f - z) * nn + z * h;
  out[idx] = hn;
  out[idx + (size_t)Nn * 128] = hn;
}

extern "C" void kernel_launch(void* const* d_in, const int* in_sizes, int n_in,
                              void* d_out, int out_size, void* d_ws, size_t ws_size,
                              hipStream_t stream) {
  const float* node = (const float*)d_in[0];
  const int* eidx = (const int*)d_in[1];
  const float* edge = (const float*)d_in[2];
  const float* hidden = (const float*)d_in[3];
  const float* W1 = (const float*)d_in[4];
  const float* g1 = (const float*)d_in[5];
  const float* b1 = (const float*)d_in[6];
  const float* W2 = (const float*)d_in[7];
  const float* g2 = (const float*)d_in[8];
  const float* b2 = (const float*)d_in[9];
  const float* W3 = (const float*)d_in[10];
  const float* g3 = (const float*)d_in[11];
  const float* b3 = (const float*)d_in[12];
  const float* W4 = (const float*)d_in[13];
  const float* g4 = (const float*)d_in[14];
  const float* b4 = (const float*)d_in[15];
  const float* bias = (const float*)d_in[16];
  const float* Wih = (const float*)d_in[17];
  const float* Whh = (const float*)d_in[18];
  const float* bih = (const float*)d_in[19];
  const float* bhh = (const float*)d_in[20];
  float* out = (float*)d_out;

  const int Nn = in_sizes[0] / 128;   // 4096
  const int E = in_sizes[2] / 16;     // 16384
  const float invE = 1.0f / (float)E;

  float* ws = (float*)d_ws;
  float* ybuf1 = ws + 0;                       // E x 256 (x1 raw) -> gram partials
  float* ybuf2 = ws + 4194304;                 // E x 256 (y2 raw) -> U -> gi/gh
  float* x3 = ws + 8388608;                    // E x 128 (y3 raw -> x3n)
  _Float16* BTf = (_Float16*)(ws + 10485760);  // 128 tiles x 16384 halves (4MB)
  float* t4 = ws + 11534336;                   // 16384
  float* stats = ws + 11550720;                // 3 x 512
  float* G3 = ws + 11552256;                   // 16384 + 128 (colsum3)
  float* sums = ws + 11568768;                 // Nn x 128
  float* cnt = ws + 12093056;                  // Nn (contiguous after sums)
  float* Tn = ws + 12097152;                   // Nn x 128
  float* stat1 = stats, *stat2 = stats + 512, *stat3 = stats + 1024;
  float* gpart = ybuf1;                        // 128 x 16512 (reuses x1 after L2)
  float* U = ybuf2;                            // 16384 x 128 (reuses y2 after L3)
  float* gi = ybuf2;                           // 4096 x 384 (after U consumed)
  float* gh = ybuf2 + 1572864;                 // 4096 x 384

  // stats zero (one small memset)
  hipMemsetAsync(stats, 0, 1536 * sizeof(float), stream);

  // L1: y1 = edge @ W1^T (+stats1)
  gemm_abt<<<dim3(4, E / 64), 256, 0, stream>>>(edge, W1, ybuf1, E, 256, 16, stat1, stat1 + 256);
  // L2: y2 = bn1relu(y1) @ W2^T (+stats2)
  gemm16<1, true><<<dim3(2, E / 128), 256, 0, stream>>>(ybuf1, W2, ybuf2, 256, 256, 256, 256,
                                                        stat1, stat1 + 256, g1, b1, invE,
                                                        stat2, stat2 + 256);
  // L3: y3 = bn2relu(y2) @ W3^T (+stats3)
  gemm16<1, true><<<dim3(1, E / 128), 256, 0, stream>>>(ybuf2, W3, x3, 256, 256, 128, 256,
                                                        stat2, stat2 + 256, g2, b2, invE,
                                                        stat3, stat3 + 256);
  // bn3 in place -> x3n
  bn_apply<<<E * 128 / 256, 256, 0, stream>>>(x3, stat3, stat3 + 256, g3, b3, E, 128);

  // Gram (+colsum3) partials -> reduce
  gram_kernel<<<128, 256, 0, stream>>>(x3, gpart, E);
  gram_reduce<<<65, 256, 0, stream>>>(gpart, G3);

  // U = W4 @ G3 (G3 symmetric)
  gemm16<0, false><<<dim3(1, 16384 / 128), 256, 0, stream>>>(W4, G3, U, 128, 128, 128, 128,
                                                             nullptr, nullptr, nullptr, nullptr,
                                                             0.f, nullptr, nullptr);
  w4_finalize<<<16384 / 4, 256, 0, stream>>>(W4, U, G3 + 16384, g4, b4, BTf, t4, invE);
  t4n_kernel<<<Nn / 8, 128, 0, stream>>>(node, t4, Tn);

  // segment sums: zero sums+cnt, count, scatter-GEMM
  hipMemsetAsync(sums, 0, ((size_t)Nn * 128 + Nn) * sizeof(float), stream);
  cnt_kernel<<<(E + 255) / 256, 256, 0, stream>>>(eidx, cnt, E);
  zgemm<<<dim3(4, E / 128), 256, 0, stream>>>(x3, node, eidx, BTf, Tn, sums);

  // GRU
  gru_gates<<<dim3(6, Nn / 128), 256, 0, stream>>>(sums, cnt, bias, hidden, Wih, Whh, gi, gh);
  gru_finalize<<<Nn * 128 / 256, 256, 0, stream>>>(gi, gh, hidden, bih, bhh, out, Nn);
}